// Round 5
// baseline (393.068 us; speedup 1.0000x reference)
//
#include <hip/hip_runtime.h>

// ---------------------------------------------------------------------------
// GCN 2-layer fused pipeline for MI355X (gfx950)
//   h1 = relu(Dinv (A+I) Dinv (x@W1) + b1)
//   out = 0.5*(h1@Wc + bc) + 0.5*((alpha*h2 + (1-alpha)*h1)@Wf + bf)
//   h2 = relu(Dinv (A+I) Dinv (h1@W2) + b2)
// R2: binned counting-sort CSR. R3: fused dinv into colv. R8: 1-dword colv.
// R10: agg one-node-per-QUARTER, depth-16 gather pipe.
// R12: occupancy-first GEMM (16-row waves, K-split 32KB LDS B, no B dbuf).
// R13: agg restructured one-node-per-8-LANES (32B/lane), 4-edge chunks in an
// A/B double-buffered pipe with colv prefetched 2 chunks ahead. Every waitcnt
// leaves the other buffer's 8 gathers + 1 colv in flight (no drain); typical
// deg-16 node = 4 chunks so pipelining engages in the COMMON case (R10's
// 1-chunk nodes had zero cross-chunk overlap; VGPR=64 proved the compiler
// had shrunk the pipe). sched_barrier(0) pins issue/consume interleave.
// Discriminates H2 (latency/MLP-bound -> -25us) vs H1 (fabric random-gather
// ceiling ~3.2 TB/s -> unchanged, agg done).
// ---------------------------------------------------------------------------

#define HID 128
#define SHIFT 9
#define RANGE 512           // nodes per bin = 1<<SHIFT
#define MAXB 256            // max bins (N <= 131072)
#define TILE 4096           // edges per stage block

typedef __bf16 bf16x8 __attribute__((ext_vector_type(8)));
typedef float  f32x4  __attribute__((ext_vector_type(4)));
typedef float  f32x2  __attribute__((ext_vector_type(2)));

__device__ __forceinline__ unsigned short f2bf(float x) {
    unsigned int b = __float_as_uint(x);
    b += 0x7fffu + ((b >> 16) & 1u);     // round-to-nearest-even
    return (unsigned short)(b >> 16);
}
__device__ __forceinline__ float bflo(unsigned int u) { return __uint_as_float(u << 16); }
__device__ __forceinline__ float bfhi(unsigned int u) { return __uint_as_float(u & 0xffff0000u); }
__device__ __forceinline__ unsigned packbf(float a, float b) {
    return (unsigned)f2bf(a) | ((unsigned)f2bf(b) << 16);
}

// --------------------------- binned CSR build ------------------------------

__global__ __launch_bounds__(256)
void bincount_kernel(const int* __restrict__ dst, int* __restrict__ bin_counts,
                     int E, int NB) {
    __shared__ int h[MAXB];
    for (int i = threadIdx.x; i < NB; i += 256) h[i] = 0;
    __syncthreads();
    const int base = blockIdx.x * TILE;
#pragma unroll
    for (int j = 0; j < TILE; j += 256) {
        int e = base + j + threadIdx.x;
        if (e < E) atomicAdd(&h[((unsigned)dst[e]) >> SHIFT], 1);
    }
    __syncthreads();
    for (int i = threadIdx.x; i < NB; i += 256) {
        int v = h[i];
        if (v) atomicAdd(&bin_counts[i], v);
    }
}

__global__ void binscan_kernel(const int* __restrict__ bin_counts,
                               int* __restrict__ bin_off, int* __restrict__ bin_cur, int NB) {
    __shared__ int sh[MAXB];
    const int t = threadIdx.x;
    int v = (t < NB) ? bin_counts[t] : 0;
    sh[t] = v;
    __syncthreads();
    for (int s = 1; s < 256; s <<= 1) {
        int x = (t >= s) ? sh[t - s] : 0;
        __syncthreads();
        sh[t] += x;
        __syncthreads();
    }
    if (t < NB) {
        int ex = sh[t] - v;     // exclusive
        bin_off[t] = ex;
        bin_cur[t] = ex;
    }
}

// Block-level binning: tile-local LDS sort by bin, then bin-sorted write-out
// in contiguous runs. pairs[i] = (dlocal<<23) | src   (src < 2^23).
__global__ __launch_bounds__(256)
void stage_kernel(const int* __restrict__ src, const int* __restrict__ dst,
                  int* __restrict__ bin_cur, unsigned* __restrict__ pairs, int E) {
    __shared__ int sh_hist[MAXB];
    __shared__ int sh_off[MAXB];
    __shared__ int sh_ex[MAXB];
    __shared__ int sh_gbase[MAXB];
    __shared__ uint2 stg[TILE];
    const int t = threadIdx.x;
    const int base = blockIdx.x * TILE;
    const int cnt = min(TILE, E - base);

    for (int i = t; i < MAXB; i += 256) sh_hist[i] = 0;
    __syncthreads();

    int s[16], d[16], r[16];
#pragma unroll
    for (int j = 0; j < 16; ++j) {
        const int k = j * 256 + t;
        if (k < cnt) {
            s[j] = src[base + k];
            d[j] = dst[base + k];
            r[j] = atomicAdd(&sh_hist[((unsigned)d[j]) >> SHIFT], 1);
        }
    }
    __syncthreads();

    const int hv = sh_hist[t];
    sh_off[t] = hv;
    __syncthreads();
    for (int st = 1; st < 256; st <<= 1) {
        int x = (t >= st) ? sh_off[t - st] : 0;
        __syncthreads();
        sh_off[t] += x;
        __syncthreads();
    }
    sh_ex[t] = sh_off[t] - hv;                      // exclusive within tile
    if (hv > 0) sh_gbase[t] = atomicAdd(&bin_cur[t], hv);
    __syncthreads();

#pragma unroll
    for (int j = 0; j < 16; ++j) {
        const int k = j * 256 + t;
        if (k < cnt) {
            int b = ((unsigned)d[j]) >> SHIFT;
            stg[sh_ex[b] + r[j]] = make_uint2((unsigned)s[j], (unsigned)d[j]);
        }
    }
    __syncthreads();

    for (int i = t; i < cnt; i += 256) {
        uint2 p = stg[i];
        int b = (int)(p.y >> SHIFT);
        unsigned w = ((p.y & (RANGE - 1)) << 23) | p.x;
        pairs[sh_gbase[b] + (i - sh_ex[b])] = w;
    }
}

// Per-bin: histogram pairs -> counts; intra-bin scan (+bin_off base) -> rowp;
// dinv from counts.
__global__ __launch_bounds__(256)
void binrowp_kernel(const unsigned* __restrict__ pairs, const int* __restrict__ bin_off,
                    float* __restrict__ dinv, int* __restrict__ rowp,
                    int N, int NB, int E) {
    __shared__ int c[RANGE];
    __shared__ int sh[256];
    const int b = blockIdx.x;
    const int t = threadIdx.x;
    const int nb = b << SHIFT;
    const int nr = min(RANGE, N - nb);
    for (int i = t; i < RANGE; i += 256) c[i] = 0;
    __syncthreads();
    const int lo = bin_off[b];
    const int hi = (b + 1 < NB) ? bin_off[b + 1] : E;
    for (int i = lo + t; i < hi; i += 256)
        atomicAdd(&c[pairs[i] >> 23], 1);
    __syncthreads();
    const int v0 = c[2 * t], v1 = c[2 * t + 1];
    const int pr = v0 + v1;
    sh[t] = pr;
    __syncthreads();
    for (int s = 1; s < 256; s <<= 1) {
        int x = (t >= s) ? sh[t - s] : 0;
        __syncthreads();
        sh[t] += x;
        __syncthreads();
    }
    const int ex = sh[t] - pr + lo;     // exclusive prefix + bin edge base
    if (2 * t < nr) {
        rowp[nb + 2 * t] = ex;
        dinv[nb + 2 * t] = rsqrtf((float)(v0 + 1));
    }
    if (2 * t + 1 < nr) {
        rowp[nb + 2 * t + 1] = ex + v0;
        dinv[nb + 2 * t + 1] = rsqrtf((float)(v1 + 1));
    }
    if (b == 0 && t == 0) rowp[N] = E;
}

// Per-bin fine scatter; emits packed (src<<15)|fixed15(dinv[src])
__global__ __launch_bounds__(256)
void fine_kernel(const unsigned* __restrict__ pairs, const int* __restrict__ bin_off,
                 const int* __restrict__ rowp, const float* __restrict__ dinv,
                 unsigned* __restrict__ colv1, int N, int NB, int E) {
    __shared__ int cur[RANGE];
    const int b = blockIdx.x;
    const int nb = b << SHIFT;
    const int nr = min(RANGE, N - nb);
    for (int i = threadIdx.x; i < nr; i += 256) cur[i] = rowp[nb + i];
    __syncthreads();
    const int lo = bin_off[b];
    const int hi = (b + 1 < NB) ? bin_off[b + 1] : E;
    for (int i = lo + threadIdx.x; i < hi; i += 256) {
        unsigned w = pairs[i];
        unsigned s = w & 0x7fffffu;
        int pos = atomicAdd(&cur[w >> 23], 1);
        unsigned w15 = __float2uint_rn(dinv[s] * 32767.0f);   // dinv in (0,1]
        colv1[pos] = (s << 15) | w15;
    }
}

// Merged prep: zero bin_counts + both weight transposes (Wt[col][k] bf16)
__global__ void prep_kernel(const float* __restrict__ W1, const float* __restrict__ W2,
                            unsigned short* __restrict__ wt1, unsigned short* __restrict__ wt2,
                            int K1, int* __restrict__ bin_counts) {
    int idx = blockIdx.x * 256 + threadIdx.x;
    if (idx < MAXB) bin_counts[idx] = 0;
    if (idx < 128 * K1) {
        int nn = idx / K1, k = idx - nn * K1;
        wt1[(size_t)nn * K1 + k] = f2bf(W1[(size_t)k * 128 + nn]);
    }
    if (idx < 128 * 128) {
        int nn = idx >> 7, k = idx & 127;
        wt2[(size_t)nn * 128 + k] = f2bf(W2[(size_t)k * 128 + nn]);
    }
}

// ------------------------------- GEMM --------------------------------------
// Out[row][col] (bf16, N x 128) = A (N x K) @ W, via Wt[col][k] bf16.
// R12 structure: 16-row waves (one 16x16 MFMA row-tile, 64 rows/block).
// B staged to LDS in K-phases of 128 (32KB). Per iteration: 8x ds_read_b128
// B fragments, fp32->bf16 cvt overlaps ds latency, A refill keeps DEPTH=4
// slots in flight on vmcnt. Swizzle: chunk kc stored at kc ^ (col&(CHH-1)).
template <bool A_BF16, int K>
__global__ __launch_bounds__(256)
void gemm_kernel(const void* __restrict__ Aptr, const unsigned short* __restrict__ Wt,
                 unsigned short* __restrict__ Out, int nrows) {
    constexpr int NIT  = K / 32;
    constexpr int DEPTH = (NIT < 4) ? NIT : 4;
    constexpr int HK   = (K > 128) ? (K / 2) : K;   // K staged per phase
    constexpr int CHH  = HK / 8;                    // 16B chunks per col/phase
    constexpr int PH   = K / HK;
    constexpr int NITP = HK / 32;
    __shared__ uint4 sB[128 * CHH];                 // 32 KB

    const int tid  = threadIdx.x;
    const int wave = tid >> 6;
    const int lane = tid & 63;
    const int q = lane >> 4;
    const int r = lane & 15;

    const int wrow = blockIdx.x * 64 + wave * 16;
    const size_t row0 = (size_t)min(wrow + r, nrows - 1);

    const unsigned short* A16 = (const unsigned short*)Aptr;
    const float*          A32 = (const float*)Aptr;

    f32x4 acc[8];
#pragma unroll
    for (int c = 0; c < 8; ++c) acc[c] = (f32x4){0.f, 0.f, 0.f, 0.f};

    bf16x8 preb[DEPTH];
    float4 pref[DEPTH][2];

    // prologue: fill the A pipe
#pragma unroll
    for (int i = 0; i < DEPTH; ++i) {
        const int kk = i * 32 + q * 8;
        if (A_BF16) {
            preb[i] = *reinterpret_cast<const bf16x8*>(A16 + row0 * K + kk);
        } else {
            pref[i][0] = *reinterpret_cast<const float4*>(A32 + row0 * K + kk);
            pref[i][1] = *reinterpret_cast<const float4*>(A32 + row0 * K + kk + 4);
        }
    }

#pragma unroll
    for (int ph = 0; ph < PH; ++ph) {
        if (ph) __syncthreads();
        // stage this phase's B half (coalesced; swizzled chunk placement)
        for (int idx = tid; idx < 128 * CHH; idx += 256) {
            const int col = idx / CHH;
            const int kc  = idx & (CHH - 1);
            const uint4 v = *reinterpret_cast<const uint4*>(
                Wt + (size_t)col * K + ph * HK + kc * 8);
            sB[col * CHH + (kc ^ (col & (CHH - 1)))] = v;
        }
        __syncthreads();

#pragma unroll
        for (int itp = 0; itp < NITP; ++itp) {
            const int git  = ph * NITP + itp;
            const int slot = git % DEPTH;

            // B fragments for this K-step from swizzled LDS
            bf16x8 bcur[8];
#pragma unroll
            for (int c = 0; c < 8; ++c) {
                const int col = c * 16 + r;
                const int chunk = (itp * 4 + q) ^ (col & (CHH - 1));
                bcur[c] = *reinterpret_cast<const bf16x8*>(&sB[col * CHH + chunk]);
            }

            // consume oldest A slot (vmcnt waits only on A pipe); cvt VALU
            // work overlaps the ds_read latency of bcur
            bf16x8 afrag;
            if (A_BF16) {
                afrag = preb[slot];
            } else {
                const float4 x0 = pref[slot][0];
                const float4 x1 = pref[slot][1];
                bf16x8 a;
                a[0] = (__bf16)x0.x; a[1] = (__bf16)x0.y; a[2] = (__bf16)x0.z; a[3] = (__bf16)x0.w;
                a[4] = (__bf16)x1.x; a[5] = (__bf16)x1.y; a[6] = (__bf16)x1.z; a[7] = (__bf16)x1.w;
                afrag = a;
            }

            // refill the pipe slot (stays in flight across iterations)
            if (git + DEPTH < NIT) {
                const int kk2 = (git + DEPTH) * 32 + q * 8;
                if (A_BF16) {
                    preb[slot] = *reinterpret_cast<const bf16x8*>(A16 + row0 * K + kk2);
                } else {
                    pref[slot][0] = *reinterpret_cast<const float4*>(A32 + row0 * K + kk2);
                    pref[slot][1] = *reinterpret_cast<const float4*>(A32 + row0 * K + kk2 + 4);
                }
            }

#pragma unroll
            for (int c = 0; c < 8; ++c)
                acc[c] = __builtin_amdgcn_mfma_f32_16x16x32_bf16(afrag, bcur[c], acc[c], 0, 0, 0);
        }
    }

#pragma unroll
    for (int v = 0; v < 4; ++v) {
        const int row = wrow + q * 4 + v;
        if (row < nrows) {
#pragma unroll
            for (int c = 0; c < 8; ++c)
                Out[(size_t)row * 128 + c * 16 + r] = f2bf(acc[c][v]);
        }
    }
}

// --------------------------- Aggregation -----------------------------------
// R13: one node per 8-LANE group (8 nodes/wave, 32 nodes/block). Lane
// c8=lane&7 owns features 16*c8..16*c8+15 (32B = two uint4 of the 256B row).
// Edge loop: 4-edge chunks, A/B double-buffered. Program order per iteration
// pins (via sched_barrier(0)) to:
//   ldcv(t+2) | ISS B(t+1) | CNS A(t) | ldcv(t+3) | ISS A(t+2) | CNS B(t+1)
// vmcnt ordered-queue: every wait leaves the other buffer's 8 gathers + 1
// colv load in flight -> no pipeline drain at chunk boundaries. Weights are
// re-shfl'd at consume (saves 16 VGPR/buffer). Typical deg-16 node = 4
// chunks -> pipelining engages in the common case. Tail edges carry cw=0 ->
// row 0 with weight 0 (branchless).

#define AGG_ISS(PF, CW, t)                                                    \
    if (((t) << 2) < me) {                                                    \
        _Pragma("unroll")                                                     \
        for (int j = 0; j < 4; ++j) {                                         \
            const unsigned cg = (unsigned)__shfl((int)(CW), gb + j);          \
            const char* p = (const char*)tbl + (((cg >> 15) << 8) + coff);    \
            PF[2 * j]     = *reinterpret_cast<const uint4*>(p);               \
            PF[2 * j + 1] = *reinterpret_cast<const uint4*>(p + 16);          \
        }                                                                     \
    }

#define AGG_CNS(PF, CW, t)                                                    \
    if (((t) << 2) < me) {                                                    \
        _Pragma("unroll")                                                     \
        for (int j = 0; j < 4; ++j) {                                         \
            const unsigned cg = (unsigned)__shfl((int)(CW), gb + j);          \
            const float w = (float)(cg & 0x7fffu) * (1.0f / 32767.0f);        \
            const uint4 u0 = PF[2 * j];                                       \
            const uint4 u1 = PF[2 * j + 1];                                   \
            A0 += (f32x2){bflo(u0.x), bfhi(u0.x)} * w;                        \
            A1 += (f32x2){bflo(u0.y), bfhi(u0.y)} * w;                        \
            A2 += (f32x2){bflo(u0.z), bfhi(u0.z)} * w;                        \
            A3 += (f32x2){bflo(u0.w), bfhi(u0.w)} * w;                        \
            A4 += (f32x2){bflo(u1.x), bfhi(u1.x)} * w;                        \
            A5 += (f32x2){bflo(u1.y), bfhi(u1.y)} * w;                        \
            A6 += (f32x2){bflo(u1.z), bfhi(u1.z)} * w;                        \
            A7 += (f32x2){bflo(u1.w), bfhi(u1.w)} * w;                        \
        }                                                                     \
    }

#define AGG_EDGE_LOOP(TBL)                                                    \
    const unsigned short* tbl = (TBL);                                        \
    const int me = end - beg;                                                 \
    auto ldcv = [&](int t) -> unsigned {                                      \
        const int idx = beg + (t << 2) + (c8 & 3);                            \
        return (idx < end) ? colv1[idx] : 0u;                                 \
    };                                                                        \
    uint4 pfA[8], pfB[8];                                                     \
    unsigned cw0 = ldcv(0);                                                   \
    unsigned cw1 = ldcv(1);                                                   \
    AGG_ISS(pfA, cw0, 0)                                                      \
    const int mych = (me + 3) >> 2;                                           \
    for (int t = 0; t < mych; t += 2) {                                       \
        const unsigned cw2 = ldcv(t + 2);                                     \
        __builtin_amdgcn_sched_barrier(0);                                    \
        AGG_ISS(pfB, cw1, t + 1)                                              \
        __builtin_amdgcn_sched_barrier(0);                                    \
        AGG_CNS(pfA, cw0, t)                                                  \
        const unsigned cw3 = ldcv(t + 3);                                     \
        __builtin_amdgcn_sched_barrier(0);                                    \
        AGG_ISS(pfA, cw2, t + 2)                                              \
        __builtin_amdgcn_sched_barrier(0);                                    \
        AGG_CNS(pfB, cw1, t + 1)                                              \
        __builtin_amdgcn_sched_barrier(0);                                    \
        cw0 = cw2; cw1 = cw3;                                                 \
    }

__device__ __forceinline__ f32x2 __shfl_xor(f32x2 v, int m) {
    return (f32x2){__shfl_xor(v[0], m), __shfl_xor(v[1], m)};
}

__global__ __launch_bounds__(256)
void agg1_kernel(const unsigned short* __restrict__ xw, const unsigned* __restrict__ colv1,
                 const int* __restrict__ rowp, const float* __restrict__ dinv,
                 const float* __restrict__ b1, const float* __restrict__ Wc,
                 const float* __restrict__ bc, uint4* __restrict__ h1,
                 float* __restrict__ outp, int n) {
    const int node = blockIdx.x * 32 + (threadIdx.x >> 3);
    if (node >= n) return;
    const int lane = threadIdx.x & 63;
    const int c8   = lane & 7;
    const int gb   = lane & 56;               // 8-lane group base
    const unsigned coff = (unsigned)c8 << 5;  // 32B per lane
    const float di = dinv[node];
    const int beg = rowp[node], end = rowp[node + 1];

    // self-loop row: issued now, consumed after the edge loop
    const char* sp = (const char*)xw + (((unsigned)node << 8) + coff);
    const uint4 su0 = *reinterpret_cast<const uint4*>(sp);
    const uint4 su1 = *reinterpret_cast<const uint4*>(sp + 16);

    f32x2 A0 = {0.f,0.f}, A1 = {0.f,0.f}, A2 = {0.f,0.f}, A3 = {0.f,0.f};
    f32x2 A4 = {0.f,0.f}, A5 = {0.f,0.f}, A6 = {0.f,0.f}, A7 = {0.f,0.f};

    AGG_EDGE_LOOP(xw)

    A0 += (f32x2){bflo(su0.x), bfhi(su0.x)} * di;
    A1 += (f32x2){bflo(su0.y), bfhi(su0.y)} * di;
    A2 += (f32x2){bflo(su0.z), bfhi(su0.z)} * di;
    A3 += (f32x2){bflo(su0.w), bfhi(su0.w)} * di;
    A4 += (f32x2){bflo(su1.x), bfhi(su1.x)} * di;
    A5 += (f32x2){bflo(su1.y), bfhi(su1.y)} * di;
    A6 += (f32x2){bflo(su1.z), bfhi(su1.z)} * di;
    A7 += (f32x2){bflo(su1.w), bfhi(su1.w)} * di;

    const float4* b4 = reinterpret_cast<const float4*>(b1);
    const float4 bb0 = b4[4*c8], bb1 = b4[4*c8+1], bb2 = b4[4*c8+2], bb3 = b4[4*c8+3];
    float a0  = fmaxf(A0[0]*di + bb0.x, 0.f), a1  = fmaxf(A0[1]*di + bb0.y, 0.f);
    float a2  = fmaxf(A1[0]*di + bb0.z, 0.f), a3  = fmaxf(A1[1]*di + bb0.w, 0.f);
    float a4  = fmaxf(A2[0]*di + bb1.x, 0.f), a5  = fmaxf(A2[1]*di + bb1.y, 0.f);
    float a6  = fmaxf(A3[0]*di + bb1.z, 0.f), a7  = fmaxf(A3[1]*di + bb1.w, 0.f);
    float a8  = fmaxf(A4[0]*di + bb2.x, 0.f), a9  = fmaxf(A4[1]*di + bb2.y, 0.f);
    float a10 = fmaxf(A5[0]*di + bb2.z, 0.f), a11 = fmaxf(A5[1]*di + bb2.w, 0.f);
    float a12 = fmaxf(A6[0]*di + bb3.x, 0.f), a13 = fmaxf(A6[1]*di + bb3.y, 0.f);
    float a14 = fmaxf(A7[0]*di + bb3.z, 0.f), a15 = fmaxf(A7[1]*di + bb3.w, 0.f);

    h1[((unsigned)node << 4) + 2*c8] =
        make_uint4(packbf(a0,a1), packbf(a2,a3), packbf(a4,a5), packbf(a6,a7));
    h1[((unsigned)node << 4) + 2*c8 + 1] =
        make_uint4(packbf(a8,a9), packbf(a10,a11), packbf(a12,a13), packbf(a14,a15));

    const float4* w4 = reinterpret_cast<const float4*>(Wc);
    float c0 = 0.f, c1 = 0.f;
    {
        const float av[16] = {a0,a1,a2,a3,a4,a5,a6,a7,a8,a9,a10,a11,a12,a13,a14,a15};
#pragma unroll
        for (int j = 0; j < 8; ++j) {
            const float4 w = w4[8*c8 + j];
            c0 += av[2*j]*w.x + av[2*j+1]*w.z;
            c1 += av[2*j]*w.y + av[2*j+1]*w.w;
        }
    }
#pragma unroll
    for (int off = 1; off < 8; off <<= 1) {        // group-local reduce
        c0 += __shfl_xor(c0, off);
        c1 += __shfl_xor(c1, off);
    }
    if (c8 == 0) {
        outp[2 * (size_t)node]     = 0.5f * (c0 + bc[0]);
        outp[2 * (size_t)node + 1] = 0.5f * (c1 + bc[1]);
    }
}

__global__ __launch_bounds__(256)
void agg2_kernel(const unsigned short* __restrict__ xw2, const uint4* __restrict__ h1,
                 const unsigned* __restrict__ colv1, const int* __restrict__ rowp,
                 const float* __restrict__ dinv, const float* __restrict__ b2,
                 const float* __restrict__ Wf, const float* __restrict__ bfv,
                 const float* __restrict__ hnode, float* __restrict__ outp, int n) {
    const int node = blockIdx.x * 32 + (threadIdx.x >> 3);
    if (node >= n) return;
    const int lane = threadIdx.x & 63;
    const int c8   = lane & 7;
    const int gb   = lane & 56;
    const unsigned coff = (unsigned)c8 << 5;
    const float di = dinv[node];
    const int beg = rowp[node], end = rowp[node + 1];

    const char* sp = (const char*)xw2 + (((unsigned)node << 8) + coff);
    const uint4 su0 = *reinterpret_cast<const uint4*>(sp);
    const uint4 su1 = *reinterpret_cast<const uint4*>(sp + 16);

    f32x2 A0 = {0.f,0.f}, A1 = {0.f,0.f}, A2 = {0.f,0.f}, A3 = {0.f,0.f};
    f32x2 A4 = {0.f,0.f}, A5 = {0.f,0.f}, A6 = {0.f,0.f}, A7 = {0.f,0.f};

    AGG_EDGE_LOOP(xw2)

    A0 += (f32x2){bflo(su0.x), bfhi(su0.x)} * di;
    A1 += (f32x2){bflo(su0.y), bfhi(su0.y)} * di;
    A2 += (f32x2){bflo(su0.z), bfhi(su0.z)} * di;
    A3 += (f32x2){bflo(su0.w), bfhi(su0.w)} * di;
    A4 += (f32x2){bflo(su1.x), bfhi(su1.x)} * di;
    A5 += (f32x2){bflo(su1.y), bfhi(su1.y)} * di;
    A6 += (f32x2){bflo(su1.z), bfhi(su1.z)} * di;
    A7 += (f32x2){bflo(su1.w), bfhi(su1.w)} * di;

    const float4* b4 = reinterpret_cast<const float4*>(b2);
    const float4 bb0 = b4[4*c8], bb1 = b4[4*c8+1], bb2 = b4[4*c8+2], bb3 = b4[4*c8+3];
    float h2v[16];
    h2v[0]  = fmaxf(A0[0]*di + bb0.x, 0.f); h2v[1]  = fmaxf(A0[1]*di + bb0.y, 0.f);
    h2v[2]  = fmaxf(A1[0]*di + bb0.z, 0.f); h2v[3]  = fmaxf(A1[1]*di + bb0.w, 0.f);
    h2v[4]  = fmaxf(A2[0]*di + bb1.x, 0.f); h2v[5]  = fmaxf(A2[1]*di + bb1.y, 0.f);
    h2v[6]  = fmaxf(A3[0]*di + bb1.z, 0.f); h2v[7]  = fmaxf(A3[1]*di + bb1.w, 0.f);
    h2v[8]  = fmaxf(A4[0]*di + bb2.x, 0.f); h2v[9]  = fmaxf(A4[1]*di + bb2.y, 0.f);
    h2v[10] = fmaxf(A5[0]*di + bb2.z, 0.f); h2v[11] = fmaxf(A5[1]*di + bb2.w, 0.f);
    h2v[12] = fmaxf(A6[0]*di + bb3.x, 0.f); h2v[13] = fmaxf(A6[1]*di + bb3.y, 0.f);
    h2v[14] = fmaxf(A7[0]*di + bb3.z, 0.f); h2v[15] = fmaxf(A7[1]*di + bb3.w, 0.f);

    const float alpha = hnode[node];
    const float beta  = 1.f - alpha;
    const uint4 hh0 = h1[((unsigned)node << 4) + 2*c8];
    const uint4 hh1 = h1[((unsigned)node << 4) + 2*c8 + 1];
    float ha[16];
    ha[0]  = alpha*h2v[0]  + beta*bflo(hh0.x); ha[1]  = alpha*h2v[1]  + beta*bfhi(hh0.x);
    ha[2]  = alpha*h2v[2]  + beta*bflo(hh0.y); ha[3]  = alpha*h2v[3]  + beta*bfhi(hh0.y);
    ha[4]  = alpha*h2v[4]  + beta*bflo(hh0.z); ha[5]  = alpha*h2v[5]  + beta*bfhi(hh0.z);
    ha[6]  = alpha*h2v[6]  + beta*bflo(hh0.w); ha[7]  = alpha*h2v[7]  + beta*bfhi(hh0.w);
    ha[8]  = alpha*h2v[8]  + beta*bflo(hh1.x); ha[9]  = alpha*h2v[9]  + beta*bfhi(hh1.x);
    ha[10] = alpha*h2v[10] + beta*bflo(hh1.y); ha[11] = alpha*h2v[11] + beta*bfhi(hh1.y);
    ha[12] = alpha*h2v[12] + beta*bflo(hh1.z); ha[13] = alpha*h2v[13] + beta*bfhi(hh1.z);
    ha[14] = alpha*h2v[14] + beta*bflo(hh1.w); ha[15] = alpha*h2v[15] + beta*bfhi(hh1.w);

    const float4* w4 = reinterpret_cast<const float4*>(Wf);
    float f0 = 0.f, f1 = 0.f;
#pragma unroll
    for (int j = 0; j < 8; ++j) {
        const float4 w = w4[8*c8 + j];
        f0 += ha[2*j]*w.x + ha[2*j+1]*w.z;
        f1 += ha[2*j]*w.y + ha[2*j+1]*w.w;
    }
#pragma unroll
    for (int off = 1; off < 8; off <<= 1) {
        f0 += __shfl_xor(f0, off);
        f1 += __shfl_xor(f1, off);
    }
    if (c8 == 0) {
        outp[2 * (size_t)node]     += 0.5f * (f0 + bfv[0]);
        outp[2 * (size_t)node + 1] += 0.5f * (f1 + bfv[1]);
    }
}

// ------------------------------ launch -------------------------------------

extern "C" void kernel_launch(void* const* d_in, const int* in_sizes, int n_in,
                              void* d_out, int out_size, void* d_ws, size_t ws_size,
                              hipStream_t stream) {
    const float* x     = (const float*)d_in[0];
    const int*   ei    = (const int*)d_in[1];     // int32 per harness contract
    const float* hnode = (const float*)d_in[2];
    const float* W1    = (const float*)d_in[3];
    const float* b1    = (const float*)d_in[4];
    const float* W2    = (const float*)d_in[5];
    const float* b2    = (const float*)d_in[6];
    const float* Wc    = (const float*)d_in[7];
    const float* bc    = (const float*)d_in[8];
    const float* Wf    = (const float*)d_in[9];
    const float* bfv   = (const float*)d_in[10];

    const int N  = in_sizes[2];
    const int E  = in_sizes[1] / 2;
    const int K1 = in_sizes[3] / HID;   // 256 (fixed by problem shape)
    const int NB = (N + RANGE - 1) >> SHIFT;
    const int* srcv = ei;
    const int* dstv = ei + E;
    float* outp = (float*)d_out;

    char* ws = (char*)d_ws;
    size_t off = 0;
    auto alloc = [&](size_t bytes) -> char* {
        char* p = ws + off;
        off += (bytes + 255) & ~(size_t)255;
        return p;
    };
    unsigned short* xw       = (unsigned short*)alloc((size_t)N * HID * 2);  // 25.6 MB
    unsigned short* h1       = (unsigned short*)alloc((size_t)N * HID * 2);  // 25.6 MB
    float*          dinv     = (float*)alloc((size_t)N * 4);
    int*            rowp     = (int*)alloc((size_t)(N + 1) * 4);
    unsigned*       colv1    = (unsigned*)alloc((size_t)E * 4);              // 6.4 MB
    unsigned*       pairs    = (unsigned*)alloc((size_t)E * 4);              // 6.4 MB
    int*            bin_counts = (int*)alloc(MAXB * 4);
    int*            bin_off    = (int*)alloc(MAXB * 4);
    int*            bin_cur    = (int*)alloc(MAXB * 4);
    unsigned short* wt1      = (unsigned short*)alloc((size_t)HID * K1 * 2);
    unsigned short* wt2      = (unsigned short*)alloc((size_t)HID * HID * 2);

    prep_kernel<<<(HID * K1 + 255) / 256, 256, 0, stream>>>(W1, W2, wt1, wt2, K1, bin_counts);

    const int ntiles = (E + TILE - 1) / TILE;
    bincount_kernel<<<ntiles, 256, 0, stream>>>(dstv, bin_counts, E, NB);
    binscan_kernel<<<1, 256, 0, stream>>>(bin_counts, bin_off, bin_cur, NB);
    stage_kernel<<<ntiles, 256, 0, stream>>>(srcv, dstv, bin_cur, pairs, E);
    binrowp_kernel<<<NB, 256, 0, stream>>>(pairs, bin_off, dinv, rowp, N, NB, E);
    fine_kernel<<<NB, 256, 0, stream>>>(pairs, bin_off, rowp, dinv, colv1, N, NB, E);

    gemm_kernel<false, 256><<<(N + 63) / 64, 256, 0, stream>>>((const void*)x, wt1, xw, N);
    agg1_kernel<<<(N + 31) / 32, 256, 0, stream>>>(xw, colv1, rowp, dinv,
                                                   b1, Wc, bc, (uint4*)h1, outp, N);
    gemm_kernel<true, 128><<<(N + 63) / 64, 256, 0, stream>>>((const void*)h1, wt2, xw, N);
    agg2_kernel<<<(N + 31) / 32, 256, 0, stream>>>(xw, (const uint4*)h1, colv1,
                                                   rowp, dinv, b2, Wf, bfv, hnode, outp, N);
}

// Round 8
// 381.070 us; speedup vs baseline: 1.0315x; 1.0315x over previous
//
#include <hip/hip_runtime.h>

// ---------------------------------------------------------------------------
// GCN 2-layer fused pipeline for MI355X (gfx950)
//   h1 = relu(Dinv (A+I) Dinv (x@W1) + b1)
//   out = 0.5*(h1@Wc + bc) + 0.5*((alpha*h2 + (1-alpha)*h1)@Wf + bf)
//   h2 = relu(Dinv (A+I) Dinv (h1@W2) + b2)
// R2: binned counting-sort CSR. R3/R8: packed colv. R10: agg one-node-per-
// QUARTER depth-16 pipe (61/60us). R12: occupancy-first GEMM (16-row waves,
// K-split 32KB LDS B). R13 REGRESSED (8-lane dbuf collapsed; reverted).
// R14 FAILED CORRECTNESS: self-loop gated on q4==0 (stale one-node-per-wave
// idiom) -> 3/4 of nodes lost the self term (absmax 0.18). R15 = R14 with
// per-quarter self-loop restored (ws = act ? 1 : 0).
// (R15 resubmit: previous round failed on GPU acquisition, never measured.)
// R14/R15 design: (a) dinv[src] pre-scale folded into GEMM epilogue
// (msgs = (dinv_s*xw_s)*dinv_d factorizes) -> agg consume is pure v_pk_add,
// colv = bare src. (b) tail slots gather a ZEROED row N (xw alloc N+1 rows)
// -> branchless. (c) persistent grid-stride agg (2048 blocks).
// ---------------------------------------------------------------------------

#define HID 128
#define SHIFT 9
#define RANGE 512           // nodes per bin = 1<<SHIFT
#define MAXB 256            // max bins (N <= 131072)
#define TILE 4096           // edges per stage block

typedef __bf16 bf16x8 __attribute__((ext_vector_type(8)));
typedef float  f32x4  __attribute__((ext_vector_type(4)));
typedef float  f32x2  __attribute__((ext_vector_type(2)));

__device__ __forceinline__ unsigned short f2bf(float x) {
    unsigned int b = __float_as_uint(x);
    b += 0x7fffu + ((b >> 16) & 1u);     // round-to-nearest-even
    return (unsigned short)(b >> 16);
}
__device__ __forceinline__ float bflo(unsigned int u) { return __uint_as_float(u << 16); }
__device__ __forceinline__ float bfhi(unsigned int u) { return __uint_as_float(u & 0xffff0000u); }
__device__ __forceinline__ unsigned packbf(float a, float b) {
    return (unsigned)f2bf(a) | ((unsigned)f2bf(b) << 16);
}

// --------------------------- binned CSR build ------------------------------

__global__ __launch_bounds__(256)
void bincount_kernel(const int* __restrict__ dst, int* __restrict__ bin_counts,
                     int E, int NB) {
    __shared__ int h[MAXB];
    for (int i = threadIdx.x; i < NB; i += 256) h[i] = 0;
    __syncthreads();
    const int base = blockIdx.x * TILE;
#pragma unroll
    for (int j = 0; j < TILE; j += 256) {
        int e = base + j + threadIdx.x;
        if (e < E) atomicAdd(&h[((unsigned)dst[e]) >> SHIFT], 1);
    }
    __syncthreads();
    for (int i = threadIdx.x; i < NB; i += 256) {
        int v = h[i];
        if (v) atomicAdd(&bin_counts[i], v);
    }
}

__global__ void binscan_kernel(const int* __restrict__ bin_counts,
                               int* __restrict__ bin_off, int* __restrict__ bin_cur, int NB) {
    __shared__ int sh[MAXB];
    const int t = threadIdx.x;
    int v = (t < NB) ? bin_counts[t] : 0;
    sh[t] = v;
    __syncthreads();
    for (int s = 1; s < 256; s <<= 1) {
        int x = (t >= s) ? sh[t - s] : 0;
        __syncthreads();
        sh[t] += x;
        __syncthreads();
    }
    if (t < NB) {
        int ex = sh[t] - v;     // exclusive
        bin_off[t] = ex;
        bin_cur[t] = ex;
    }
}

// Block-level binning: tile-local LDS sort by bin, then bin-sorted write-out
// in contiguous runs. pairs[i] = (dlocal<<23) | src   (src < 2^23).
__global__ __launch_bounds__(256)
void stage_kernel(const int* __restrict__ src, const int* __restrict__ dst,
                  int* __restrict__ bin_cur, unsigned* __restrict__ pairs, int E) {
    __shared__ int sh_hist[MAXB];
    __shared__ int sh_off[MAXB];
    __shared__ int sh_ex[MAXB];
    __shared__ int sh_gbase[MAXB];
    __shared__ uint2 stg[TILE];
    const int t = threadIdx.x;
    const int base = blockIdx.x * TILE;
    const int cnt = min(TILE, E - base);

    for (int i = t; i < MAXB; i += 256) sh_hist[i] = 0;
    __syncthreads();

    int s[16], d[16], r[16];
#pragma unroll
    for (int j = 0; j < 16; ++j) {
        const int k = j * 256 + t;
        if (k < cnt) {
            s[j] = src[base + k];
            d[j] = dst[base + k];
            r[j] = atomicAdd(&sh_hist[((unsigned)d[j]) >> SHIFT], 1);
        }
    }
    __syncthreads();

    const int hv = sh_hist[t];
    sh_off[t] = hv;
    __syncthreads();
    for (int st = 1; st < 256; st <<= 1) {
        int x = (t >= st) ? sh_off[t - st] : 0;
        __syncthreads();
        sh_off[t] += x;
        __syncthreads();
    }
    sh_ex[t] = sh_off[t] - hv;                      // exclusive within tile
    if (hv > 0) sh_gbase[t] = atomicAdd(&bin_cur[t], hv);
    __syncthreads();

#pragma unroll
    for (int j = 0; j < 16; ++j) {
        const int k = j * 256 + t;
        if (k < cnt) {
            int b = ((unsigned)d[j]) >> SHIFT;
            stg[sh_ex[b] + r[j]] = make_uint2((unsigned)s[j], (unsigned)d[j]);
        }
    }
    __syncthreads();

    for (int i = t; i < cnt; i += 256) {
        uint2 p = stg[i];
        int b = (int)(p.y >> SHIFT);
        unsigned w = ((p.y & (RANGE - 1)) << 23) | p.x;
        pairs[sh_gbase[b] + (i - sh_ex[b])] = w;
    }
}

// Per-bin: histogram pairs -> counts; intra-bin scan (+bin_off base) -> rowp;
// dinv from counts.
__global__ __launch_bounds__(256)
void binrowp_kernel(const unsigned* __restrict__ pairs, const int* __restrict__ bin_off,
                    float* __restrict__ dinv, int* __restrict__ rowp,
                    int N, int NB, int E) {
    __shared__ int c[RANGE];
    __shared__ int sh[256];
    const int b = blockIdx.x;
    const int t = threadIdx.x;
    const int nb = b << SHIFT;
    const int nr = min(RANGE, N - nb);
    for (int i = t; i < RANGE; i += 256) c[i] = 0;
    __syncthreads();
    const int lo = bin_off[b];
    const int hi = (b + 1 < NB) ? bin_off[b + 1] : E;
    for (int i = lo + t; i < hi; i += 256)
        atomicAdd(&c[pairs[i] >> 23], 1);
    __syncthreads();
    const int v0 = c[2 * t], v1 = c[2 * t + 1];
    const int pr = v0 + v1;
    sh[t] = pr;
    __syncthreads();
    for (int s = 1; s < 256; s <<= 1) {
        int x = (t >= s) ? sh[t - s] : 0;
        __syncthreads();
        sh[t] += x;
        __syncthreads();
    }
    const int ex = sh[t] - pr + lo;     // exclusive prefix + bin edge base
    if (2 * t < nr) {
        rowp[nb + 2 * t] = ex;
        dinv[nb + 2 * t] = rsqrtf((float)(v0 + 1));
    }
    if (2 * t + 1 < nr) {
        rowp[nb + 2 * t + 1] = ex + v0;
        dinv[nb + 2 * t + 1] = rsqrtf((float)(v1 + 1));
    }
    if (b == 0 && t == 0) rowp[N] = E;
}

// Per-bin fine scatter; emits bare src index (dinv[src] is pre-scaled into
// the gathered rows by the GEMM epilogue)
__global__ __launch_bounds__(256)
void fine_kernel(const unsigned* __restrict__ pairs, const int* __restrict__ bin_off,
                 const int* __restrict__ rowp, const float* __restrict__ dinv,
                 unsigned* __restrict__ colv1, int N, int NB, int E) {
    __shared__ int cur[RANGE];
    const int b = blockIdx.x;
    const int nb = b << SHIFT;
    const int nr = min(RANGE, N - nb);
    for (int i = threadIdx.x; i < nr; i += 256) cur[i] = rowp[nb + i];
    __syncthreads();
    const int lo = bin_off[b];
    const int hi = (b + 1 < NB) ? bin_off[b + 1] : E;
    for (int i = lo + threadIdx.x; i < hi; i += 256) {
        unsigned w = pairs[i];
        int pos = atomicAdd(&cur[w >> 23], 1);
        colv1[pos] = w & 0x7fffffu;     // src index only
    }
}

// Merged prep: zero bin_counts + both weight transposes + zero pad row N of
// the xw table (tail slots in agg gather row N with pure adds).
__global__ void prep_kernel(const float* __restrict__ W1, const float* __restrict__ W2,
                            unsigned short* __restrict__ wt1, unsigned short* __restrict__ wt2,
                            int K1, int* __restrict__ bin_counts,
                            unsigned short* __restrict__ xw_pad, int N) {
    int idx = blockIdx.x * 256 + threadIdx.x;
    if (idx < MAXB) bin_counts[idx] = 0;
    if (idx < HID) xw_pad[(size_t)N * HID + idx] = 0;   // zero row N
    if (idx < 128 * K1) {
        int nn = idx / K1, k = idx - nn * K1;
        wt1[(size_t)nn * K1 + k] = f2bf(W1[(size_t)k * 128 + nn]);
    }
    if (idx < 128 * 128) {
        int nn = idx >> 7, k = idx & 127;
        wt2[(size_t)nn * 128 + k] = f2bf(W2[(size_t)k * 128 + nn]);
    }
}

// ------------------------------- GEMM --------------------------------------
// Out[row][col] (bf16, N x 128) = (A (N x K) @ W) * dinv[row]  (pre-scale for
// the agg gather). R12 structure: 16-row waves, K-split 32KB LDS B staging,
// DEPTH=4 A register pipe on vmcnt, 8x ds_read_b128 B per iteration.
template <bool A_BF16, int K>
__global__ __launch_bounds__(256)
void gemm_kernel(const void* __restrict__ Aptr, const unsigned short* __restrict__ Wt,
                 const float* __restrict__ dinvv, unsigned short* __restrict__ Out,
                 int nrows) {
    constexpr int NIT  = K / 32;
    constexpr int DEPTH = (NIT < 4) ? NIT : 4;
    constexpr int HK   = (K > 128) ? (K / 2) : K;   // K staged per phase
    constexpr int CHH  = HK / 8;                    // 16B chunks per col/phase
    constexpr int PH   = K / HK;
    constexpr int NITP = HK / 32;
    __shared__ uint4 sB[128 * CHH];                 // 32 KB

    const int tid  = threadIdx.x;
    const int wave = tid >> 6;
    const int lane = tid & 63;
    const int q = lane >> 4;
    const int r = lane & 15;

    const int wrow = blockIdx.x * 64 + wave * 16;
    const size_t row0 = (size_t)min(wrow + r, nrows - 1);

    const unsigned short* A16 = (const unsigned short*)Aptr;
    const float*          A32 = (const float*)Aptr;

    f32x4 acc[8];
#pragma unroll
    for (int c = 0; c < 8; ++c) acc[c] = (f32x4){0.f, 0.f, 0.f, 0.f};

    bf16x8 preb[DEPTH];
    float4 pref[DEPTH][2];

    // prologue: fill the A pipe
#pragma unroll
    for (int i = 0; i < DEPTH; ++i) {
        const int kk = i * 32 + q * 8;
        if (A_BF16) {
            preb[i] = *reinterpret_cast<const bf16x8*>(A16 + row0 * K + kk);
        } else {
            pref[i][0] = *reinterpret_cast<const float4*>(A32 + row0 * K + kk);
            pref[i][1] = *reinterpret_cast<const float4*>(A32 + row0 * K + kk + 4);
        }
    }

#pragma unroll
    for (int ph = 0; ph < PH; ++ph) {
        if (ph) __syncthreads();
        // stage this phase's B half (coalesced; swizzled chunk placement)
        for (int idx = tid; idx < 128 * CHH; idx += 256) {
            const int col = idx / CHH;
            const int kc  = idx & (CHH - 1);
            const uint4 v = *reinterpret_cast<const uint4*>(
                Wt + (size_t)col * K + ph * HK + kc * 8);
            sB[col * CHH + (kc ^ (col & (CHH - 1)))] = v;
        }
        __syncthreads();

#pragma unroll
        for (int itp = 0; itp < NITP; ++itp) {
            const int git  = ph * NITP + itp;
            const int slot = git % DEPTH;

            // B fragments for this K-step from swizzled LDS
            bf16x8 bcur[8];
#pragma unroll
            for (int c = 0; c < 8; ++c) {
                const int col = c * 16 + r;
                const int chunk = (itp * 4 + q) ^ (col & (CHH - 1));
                bcur[c] = *reinterpret_cast<const bf16x8*>(&sB[col * CHH + chunk]);
            }

            // consume oldest A slot (vmcnt waits only on A pipe); cvt VALU
            // work overlaps the ds_read latency of bcur
            bf16x8 afrag;
            if (A_BF16) {
                afrag = preb[slot];
            } else {
                const float4 x0 = pref[slot][0];
                const float4 x1 = pref[slot][1];
                bf16x8 a;
                a[0] = (__bf16)x0.x; a[1] = (__bf16)x0.y; a[2] = (__bf16)x0.z; a[3] = (__bf16)x0.w;
                a[4] = (__bf16)x1.x; a[5] = (__bf16)x1.y; a[6] = (__bf16)x1.z; a[7] = (__bf16)x1.w;
                afrag = a;
            }

            // refill the pipe slot (stays in flight across iterations)
            if (git + DEPTH < NIT) {
                const int kk2 = (git + DEPTH) * 32 + q * 8;
                if (A_BF16) {
                    preb[slot] = *reinterpret_cast<const bf16x8*>(A16 + row0 * K + kk2);
                } else {
                    pref[slot][0] = *reinterpret_cast<const float4*>(A32 + row0 * K + kk2);
                    pref[slot][1] = *reinterpret_cast<const float4*>(A32 + row0 * K + kk2 + 4);
                }
            }

#pragma unroll
            for (int c = 0; c < 8; ++c)
                acc[c] = __builtin_amdgcn_mfma_f32_16x16x32_bf16(afrag, bcur[c], acc[c], 0, 0, 0);
        }
    }

#pragma unroll
    for (int v = 0; v < 4; ++v) {
        const int row = wrow + q * 4 + v;
        if (row < nrows) {
            const float sc = dinvv[row];
#pragma unroll
            for (int c = 0; c < 8; ++c)
                Out[(size_t)row * 128 + c * 16 + r] = f2bf(acc[c][v] * sc);
        }
    }
}

// --------------------------- Aggregation -----------------------------------
// R15: R10 quarter structure (one node per 16-lane quarter), persistent
// grid-stride (2048 blocks). Rows gathered are PRE-SCALED by dinv[src]
// (gemm epilogue), so consume is pure v_pk_add. Tail slots gather the
// zeroed row N (branchless). Self-loop added PER QUARTER (each quarter owns
// its own node — R14's q4==0 gating was the correctness bug).

#define AGG_ISSUE(g, TBL)                                                     \
    if ((g) * 4 < cnt) {                                                      \
        _Pragma("unroll")                                                     \
        for (int j = 0; j < 4; ++j) {                                         \
            const int sl = (g) * 4 + j;                                       \
            const unsigned cg = (unsigned)__shfl((int)cw, qb + sl);           \
            pf[sl] = *reinterpret_cast<const uint4*>(                         \
                (const char*)(TBL) + (((size_t)cg << 8) + coff));             \
        }                                                                     \
    }

#define AGG_CONS(g)                                                          \
    if ((g) * 4 < cnt) {                                                     \
        _Pragma("unroll")                                                    \
        for (int j = 0; j < 4; ++j) {                                        \
            const uint4 uu = pf[(g) * 4 + j];                                \
            A0 += (f32x2){bflo(uu.x), bfhi(uu.x)};                           \
            A1 += (f32x2){bflo(uu.y), bfhi(uu.y)};                           \
            A2 += (f32x2){bflo(uu.z), bfhi(uu.z)};                           \
            A3 += (f32x2){bflo(uu.w), bfhi(uu.w)};                           \
        }                                                                    \
    }

#define AGG_EDGE_LOOP(TBL)                                                   \
    unsigned cw = (beg + c < end) ? colv1[beg + c] : (unsigned)n;            \
    for (int eb = beg; eb < end; eb += 16) {                                 \
        const int cnt = end - eb;                                            \
        AGG_ISSUE(0, TBL) AGG_ISSUE(1, TBL) AGG_ISSUE(2, TBL) AGG_ISSUE(3, TBL) \
        unsigned cw_next = (unsigned)n;                                      \
        if (eb + 16 + c < end) cw_next = colv1[eb + 16 + c];                 \
        AGG_CONS(0) AGG_CONS(1) AGG_CONS(2) AGG_CONS(3)                      \
        cw = cw_next;                                                        \
    }

__device__ __forceinline__ f32x2 __shfl_xor(f32x2 v, int m) {
    return (f32x2){__shfl_xor(v[0], m), __shfl_xor(v[1], m)};
}

__global__ __launch_bounds__(256)
void agg1_kernel(const unsigned short* __restrict__ xw, const unsigned* __restrict__ colv1,
                 const int* __restrict__ rowp, const float* __restrict__ dinv,
                 const float* __restrict__ b1, const float* __restrict__ Wc,
                 const float* __restrict__ bc, uint4* __restrict__ h1,
                 float* __restrict__ outp, int n) {
    const int lane = threadIdx.x & 63;
    const int wid  = threadIdx.x >> 6;
    const int c    = lane & 15;
    const int q4   = lane >> 4;
    const int qb   = lane & 48;               // quarter base lane
    const unsigned coff = (unsigned)c << 4;

    for (int bn = blockIdx.x * 16 + wid * 4; bn < n; bn += gridDim.x * 16) {
        const int node = bn + q4;
        const bool act = node < n;
        const int nc   = act ? node : (n - 1);
        const float di = act ? dinv[nc] : 0.f;
        const int beg = act ? rowp[nc] : 0;
        const int end = act ? rowp[nc + 1] : 0;

        // self-loop row (pre-scaled by dinv[node]); EVERY quarter adds its own
        const float ws = act ? 1.f : 0.f;
        const uint4 su = *reinterpret_cast<const uint4*>(
            (const char*)xw + (((size_t)nc << 8) + coff));

        f32x2 A0 = {0.f,0.f}, A1 = {0.f,0.f}, A2 = {0.f,0.f}, A3 = {0.f,0.f};
        uint4 pf[16];

        AGG_EDGE_LOOP(xw)

        A0 += (f32x2){bflo(su.x), bfhi(su.x)} * ws;
        A1 += (f32x2){bflo(su.y), bfhi(su.y)} * ws;
        A2 += (f32x2){bflo(su.z), bfhi(su.z)} * ws;
        A3 += (f32x2){bflo(su.w), bfhi(su.w)} * ws;

        const float4 bb0 = reinterpret_cast<const float4*>(b1)[2*c];
        const float4 bb1 = reinterpret_cast<const float4*>(b1)[2*c + 1];
        float a0 = fmaxf(A0[0]*di + bb0.x, 0.f), a1 = fmaxf(A0[1]*di + bb0.y, 0.f);
        float a2 = fmaxf(A1[0]*di + bb0.z, 0.f), a3 = fmaxf(A1[1]*di + bb0.w, 0.f);
        float a4 = fmaxf(A2[0]*di + bb1.x, 0.f), a5 = fmaxf(A2[1]*di + bb1.y, 0.f);
        float a6 = fmaxf(A3[0]*di + bb1.z, 0.f), a7 = fmaxf(A3[1]*di + bb1.w, 0.f);

        if (act)
            h1[((size_t)nc << 4) + c] =
                make_uint4(packbf(a0,a1), packbf(a2,a3), packbf(a4,a5), packbf(a6,a7));

        const float4 w0 = reinterpret_cast<const float4*>(Wc)[4*c];
        const float4 w1 = reinterpret_cast<const float4*>(Wc)[4*c + 1];
        const float4 w2 = reinterpret_cast<const float4*>(Wc)[4*c + 2];
        const float4 w3 = reinterpret_cast<const float4*>(Wc)[4*c + 3];
        float c0 = a0*w0.x + a1*w0.z + a2*w1.x + a3*w1.z
                 + a4*w2.x + a5*w2.z + a6*w3.x + a7*w3.z;
        float c1 = a0*w0.y + a1*w0.w + a2*w1.y + a3*w1.w
                 + a4*w2.y + a5*w2.w + a6*w3.y + a7*w3.w;
#pragma unroll
        for (int off = 1; off < 16; off <<= 1) {       // quarter-local reduce
            c0 += __shfl_xor(c0, off);
            c1 += __shfl_xor(c1, off);
        }
        if (act && c == 0) {
            outp[2 * (size_t)nc]     = 0.5f * (c0 + bc[0]);
            outp[2 * (size_t)nc + 1] = 0.5f * (c1 + bc[1]);
        }
    }
}

__global__ __launch_bounds__(256)
void agg2_kernel(const unsigned short* __restrict__ xw2, const uint4* __restrict__ h1,
                 const unsigned* __restrict__ colv1, const int* __restrict__ rowp,
                 const float* __restrict__ dinv, const float* __restrict__ b2,
                 const float* __restrict__ Wf, const float* __restrict__ bfv,
                 const float* __restrict__ hnode, float* __restrict__ outp, int n) {
    const int lane = threadIdx.x & 63;
    const int wid  = threadIdx.x >> 6;
    const int c    = lane & 15;
    const int q4   = lane >> 4;
    const int qb   = lane & 48;
    const unsigned coff = (unsigned)c << 4;

    for (int bn = blockIdx.x * 16 + wid * 4; bn < n; bn += gridDim.x * 16) {
        const int node = bn + q4;
        const bool act = node < n;
        const int nc   = act ? node : (n - 1);
        const float di = act ? dinv[nc] : 0.f;
        const int beg = act ? rowp[nc] : 0;
        const int end = act ? rowp[nc + 1] : 0;

        const float ws = act ? 1.f : 0.f;   // per-quarter self-loop (R15 fix)
        const uint4 su = *reinterpret_cast<const uint4*>(
            (const char*)xw2 + (((size_t)nc << 8) + coff));

        f32x2 A0 = {0.f,0.f}, A1 = {0.f,0.f}, A2 = {0.f,0.f}, A3 = {0.f,0.f};
        uint4 pf[16];

        AGG_EDGE_LOOP(xw2)

        A0 += (f32x2){bflo(su.x), bfhi(su.x)} * ws;
        A1 += (f32x2){bflo(su.y), bfhi(su.y)} * ws;
        A2 += (f32x2){bflo(su.z), bfhi(su.z)} * ws;
        A3 += (f32x2){bflo(su.w), bfhi(su.w)} * ws;

        const float4 bb0 = reinterpret_cast<const float4*>(b2)[2*c];
        const float4 bb1 = reinterpret_cast<const float4*>(b2)[2*c + 1];
        float h20 = fmaxf(A0[0]*di + bb0.x, 0.f), h21 = fmaxf(A0[1]*di + bb0.y, 0.f);
        float h22 = fmaxf(A1[0]*di + bb0.z, 0.f), h23 = fmaxf(A1[1]*di + bb0.w, 0.f);
        float h24 = fmaxf(A2[0]*di + bb1.x, 0.f), h25 = fmaxf(A2[1]*di + bb1.y, 0.f);
        float h26 = fmaxf(A3[0]*di + bb1.z, 0.f), h27 = fmaxf(A3[1]*di + bb1.w, 0.f);

        const float alpha = act ? hnode[nc] : 0.f;
        const float beta  = 1.f - alpha;
        const uint4 hh = h1[((size_t)nc << 4) + c];
        const float ha0 = alpha*h20 + beta*bflo(hh.x);
        const float ha1 = alpha*h21 + beta*bfhi(hh.x);
        const float ha2 = alpha*h22 + beta*bflo(hh.y);
        const float ha3 = alpha*h23 + beta*bfhi(hh.y);
        const float ha4 = alpha*h24 + beta*bflo(hh.z);
        const float ha5 = alpha*h25 + beta*bfhi(hh.z);
        const float ha6 = alpha*h26 + beta*bflo(hh.w);
        const float ha7 = alpha*h27 + beta*bfhi(hh.w);

        const float4 w0 = reinterpret_cast<const float4*>(Wf)[4*c];
        const float4 w1 = reinterpret_cast<const float4*>(Wf)[4*c + 1];
        const float4 w2 = reinterpret_cast<const float4*>(Wf)[4*c + 2];
        const float4 w3 = reinterpret_cast<const float4*>(Wf)[4*c + 3];
        float f0 = ha0*w0.x + ha1*w0.z + ha2*w1.x + ha3*w1.z
                 + ha4*w2.x + ha5*w2.z + ha6*w3.x + ha7*w3.z;
        float f1 = ha0*w0.y + ha1*w0.w + ha2*w1.y + ha3*w1.w
                 + ha4*w2.y + ha5*w2.w + ha6*w3.y + ha7*w3.w;
#pragma unroll
        for (int off = 1; off < 16; off <<= 1) {
            f0 += __shfl_xor(f0, off);
            f1 += __shfl_xor(f1, off);
        }
        if (act && c == 0) {
            outp[2 * (size_t)nc]     += 0.5f * (f0 + bfv[0]);
            outp[2 * (size_t)nc + 1] += 0.5f * (f1 + bfv[1]);
        }
    }
}

// ------------------------------ launch -------------------------------------

extern "C" void kernel_launch(void* const* d_in, const int* in_sizes, int n_in,
                              void* d_out, int out_size, void* d_ws, size_t ws_size,
                              hipStream_t stream) {
    const float* x     = (const float*)d_in[0];
    const int*   ei    = (const int*)d_in[1];     // int32 per harness contract
    const float* hnode = (const float*)d_in[2];
    const float* W1    = (const float*)d_in[3];
    const float* b1    = (const float*)d_in[4];
    const float* W2    = (const float*)d_in[5];
    const float* b2    = (const float*)d_in[6];
    const float* Wc    = (const float*)d_in[7];
    const float* bc    = (const float*)d_in[8];
    const float* Wf    = (const float*)d_in[9];
    const float* bfv   = (const float*)d_in[10];

    const int N  = in_sizes[2];
    const int E  = in_sizes[1] / 2;
    const int K1 = in_sizes[3] / HID;   // 256 (fixed by problem shape)
    const int NB = (N + RANGE - 1) >> SHIFT;
    const int* srcv = ei;
    const int* dstv = ei + E;
    float* outp = (float*)d_out;

    char* ws = (char*)d_ws;
    size_t off = 0;
    auto alloc = [&](size_t bytes) -> char* {
        char* p = ws + off;
        off += (bytes + 255) & ~(size_t)255;
        return p;
    };
    unsigned short* xw       = (unsigned short*)alloc((size_t)(N + 1) * HID * 2); // +pad row N
    unsigned short* h1       = (unsigned short*)alloc((size_t)N * HID * 2);
    float*          dinv     = (float*)alloc((size_t)N * 4);
    int*            rowp     = (int*)alloc((size_t)(N + 1) * 4);
    unsigned*       colv1    = (unsigned*)alloc((size_t)E * 4);
    unsigned*       pairs    = (unsigned*)alloc((size_t)E * 4);
    int*            bin_counts = (int*)alloc(MAXB * 4);
    int*            bin_off    = (int*)alloc(MAXB * 4);
    int*            bin_cur    = (int*)alloc(MAXB * 4);
    unsigned short* wt1      = (unsigned short*)alloc((size_t)HID * K1 * 2);
    unsigned short* wt2      = (unsigned short*)alloc((size_t)HID * HID * 2);

    prep_kernel<<<(HID * K1 + 255) / 256, 256, 0, stream>>>(W1, W2, wt1, wt2, K1,
                                                            bin_counts, xw, N);

    const int ntiles = (E + TILE - 1) / TILE;
    bincount_kernel<<<ntiles, 256, 0, stream>>>(dstv, bin_counts, E, NB);
    binscan_kernel<<<1, 256, 0, stream>>>(bin_counts, bin_off, bin_cur, NB);
    stage_kernel<<<ntiles, 256, 0, stream>>>(srcv, dstv, bin_cur, pairs, E);
    binrowp_kernel<<<NB, 256, 0, stream>>>(pairs, bin_off, dinv, rowp, N, NB, E);
    fine_kernel<<<NB, 256, 0, stream>>>(pairs, bin_off, rowp, dinv, colv1, N, NB, E);

    const int agrid = min((N + 15) / 16, 2048);
    gemm_kernel<false, 256><<<(N + 63) / 64, 256, 0, stream>>>((const void*)x, wt1, dinv, xw, N);
    agg1_kernel<<<agrid, 256, 0, stream>>>(xw, colv1, rowp, dinv,
                                           b1, Wc, bc, (uint4*)h1, outp, N);
    gemm_kernel<true, 128><<<(N + 63) / 64, 256, 0, stream>>>((const void*)h1, wt2, dinv, xw, N);
    agg2_kernel<<<agrid, 256, 0, stream>>>(xw, (const uint4*)h1, colv1,
                                           rowp, dinv, b2, Wf, bfv, hnode, outp, N);
}

// Round 9
// 373.744 us; speedup vs baseline: 1.0517x; 1.0196x over previous
//
#include <hip/hip_runtime.h>

// ---------------------------------------------------------------------------
// GCN 2-layer fused pipeline for MI355X (gfx950)
//   h1 = relu(Dinv (A+I) Dinv (x@W1) + b1)
//   out = 0.5*(h1@Wc + bc) + 0.5*((alpha*h2 + (1-alpha)*h1)@Wf + bf)
//   h2 = relu(Dinv (A+I) Dinv (h1@W2) + b2)
// R2: binned counting-sort CSR. R10: agg one-node-per-QUARTER depth-16 pipe
// (61/60us). R12: occupancy-first GEMM (16-row waves, K-split 32KB LDS B).
// R13 REGRESSED (dbuf collapsed). R14 failed correctness (self-loop gate).
// R15: pure-add consume (dinv pre-scaled in gemm epilogue) + persistent grid
// -> agg 63/63, VALUBusy 33->27 but occupancy 34->26 (VGPR 76): VALU cut
// confirmed, persistent loop regressed residency. Gather BW pinned at
// ~3.3-3.5 TB/s across 3 structures -> memory-path floor suspected.
// R16: R15 math + R12 launch shape (one-shot blocks, no grid-stride, no
// loop-carried state). Isolates the last variable. If agg stays ~60-63us at
// restored ~34% occupancy, the random-gather path is the confirmed floor.
// ---------------------------------------------------------------------------

#define HID 128
#define SHIFT 9
#define RANGE 512           // nodes per bin = 1<<SHIFT
#define MAXB 256            // max bins (N <= 131072)
#define TILE 4096           // edges per stage block

typedef __bf16 bf16x8 __attribute__((ext_vector_type(8)));
typedef float  f32x4  __attribute__((ext_vector_type(4)));
typedef float  f32x2  __attribute__((ext_vector_type(2)));

__device__ __forceinline__ unsigned short f2bf(float x) {
    unsigned int b = __float_as_uint(x);
    b += 0x7fffu + ((b >> 16) & 1u);     // round-to-nearest-even
    return (unsigned short)(b >> 16);
}
__device__ __forceinline__ float bflo(unsigned int u) { return __uint_as_float(u << 16); }
__device__ __forceinline__ float bfhi(unsigned int u) { return __uint_as_float(u & 0xffff0000u); }
__device__ __forceinline__ unsigned packbf(float a, float b) {
    return (unsigned)f2bf(a) | ((unsigned)f2bf(b) << 16);
}

// --------------------------- binned CSR build ------------------------------

__global__ __launch_bounds__(256)
void bincount_kernel(const int* __restrict__ dst, int* __restrict__ bin_counts,
                     int E, int NB) {
    __shared__ int h[MAXB];
    for (int i = threadIdx.x; i < NB; i += 256) h[i] = 0;
    __syncthreads();
    const int base = blockIdx.x * TILE;
#pragma unroll
    for (int j = 0; j < TILE; j += 256) {
        int e = base + j + threadIdx.x;
        if (e < E) atomicAdd(&h[((unsigned)dst[e]) >> SHIFT], 1);
    }
    __syncthreads();
    for (int i = threadIdx.x; i < NB; i += 256) {
        int v = h[i];
        if (v) atomicAdd(&bin_counts[i], v);
    }
}

__global__ void binscan_kernel(const int* __restrict__ bin_counts,
                               int* __restrict__ bin_off, int* __restrict__ bin_cur, int NB) {
    __shared__ int sh[MAXB];
    const int t = threadIdx.x;
    int v = (t < NB) ? bin_counts[t] : 0;
    sh[t] = v;
    __syncthreads();
    for (int s = 1; s < 256; s <<= 1) {
        int x = (t >= s) ? sh[t - s] : 0;
        __syncthreads();
        sh[t] += x;
        __syncthreads();
    }
    if (t < NB) {
        int ex = sh[t] - v;     // exclusive
        bin_off[t] = ex;
        bin_cur[t] = ex;
    }
}

// Block-level binning: tile-local LDS sort by bin, then bin-sorted write-out
// in contiguous runs. pairs[i] = (dlocal<<23) | src   (src < 2^23).
__global__ __launch_bounds__(256)
void stage_kernel(const int* __restrict__ src, const int* __restrict__ dst,
                  int* __restrict__ bin_cur, unsigned* __restrict__ pairs, int E) {
    __shared__ int sh_hist[MAXB];
    __shared__ int sh_off[MAXB];
    __shared__ int sh_ex[MAXB];
    __shared__ int sh_gbase[MAXB];
    __shared__ uint2 stg[TILE];
    const int t = threadIdx.x;
    const int base = blockIdx.x * TILE;
    const int cnt = min(TILE, E - base);

    for (int i = t; i < MAXB; i += 256) sh_hist[i] = 0;
    __syncthreads();

    int s[16], d[16], r[16];
#pragma unroll
    for (int j = 0; j < 16; ++j) {
        const int k = j * 256 + t;
        if (k < cnt) {
            s[j] = src[base + k];
            d[j] = dst[base + k];
            r[j] = atomicAdd(&sh_hist[((unsigned)d[j]) >> SHIFT], 1);
        }
    }
    __syncthreads();

    const int hv = sh_hist[t];
    sh_off[t] = hv;
    __syncthreads();
    for (int st = 1; st < 256; st <<= 1) {
        int x = (t >= st) ? sh_off[t - st] : 0;
        __syncthreads();
        sh_off[t] += x;
        __syncthreads();
    }
    sh_ex[t] = sh_off[t] - hv;                      // exclusive within tile
    if (hv > 0) sh_gbase[t] = atomicAdd(&bin_cur[t], hv);
    __syncthreads();

#pragma unroll
    for (int j = 0; j < 16; ++j) {
        const int k = j * 256 + t;
        if (k < cnt) {
            int b = ((unsigned)d[j]) >> SHIFT;
            stg[sh_ex[b] + r[j]] = make_uint2((unsigned)s[j], (unsigned)d[j]);
        }
    }
    __syncthreads();

    for (int i = t; i < cnt; i += 256) {
        uint2 p = stg[i];
        int b = (int)(p.y >> SHIFT);
        unsigned w = ((p.y & (RANGE - 1)) << 23) | p.x;
        pairs[sh_gbase[b] + (i - sh_ex[b])] = w;
    }
}

// Per-bin: histogram pairs -> counts; intra-bin scan (+bin_off base) -> rowp;
// dinv from counts.
__global__ __launch_bounds__(256)
void binrowp_kernel(const unsigned* __restrict__ pairs, const int* __restrict__ bin_off,
                    float* __restrict__ dinv, int* __restrict__ rowp,
                    int N, int NB, int E) {
    __shared__ int c[RANGE];
    __shared__ int sh[256];
    const int b = blockIdx.x;
    const int t = threadIdx.x;
    const int nb = b << SHIFT;
    const int nr = min(RANGE, N - nb);
    for (int i = t; i < RANGE; i += 256) c[i] = 0;
    __syncthreads();
    const int lo = bin_off[b];
    const int hi = (b + 1 < NB) ? bin_off[b + 1] : E;
    for (int i = lo + t; i < hi; i += 256)
        atomicAdd(&c[pairs[i] >> 23], 1);
    __syncthreads();
    const int v0 = c[2 * t], v1 = c[2 * t + 1];
    const int pr = v0 + v1;
    sh[t] = pr;
    __syncthreads();
    for (int s = 1; s < 256; s <<= 1) {
        int x = (t >= s) ? sh[t - s] : 0;
        __syncthreads();
        sh[t] += x;
        __syncthreads();
    }
    const int ex = sh[t] - pr + lo;     // exclusive prefix + bin edge base
    if (2 * t < nr) {
        rowp[nb + 2 * t] = ex;
        dinv[nb + 2 * t] = rsqrtf((float)(v0 + 1));
    }
    if (2 * t + 1 < nr) {
        rowp[nb + 2 * t + 1] = ex + v0;
        dinv[nb + 2 * t + 1] = rsqrtf((float)(v1 + 1));
    }
    if (b == 0 && t == 0) rowp[N] = E;
}

// Per-bin fine scatter; emits bare src index (dinv[src] is pre-scaled into
// the gathered rows by the GEMM epilogue)
__global__ __launch_bounds__(256)
void fine_kernel(const unsigned* __restrict__ pairs, const int* __restrict__ bin_off,
                 const int* __restrict__ rowp, const float* __restrict__ dinv,
                 unsigned* __restrict__ colv1, int N, int NB, int E) {
    __shared__ int cur[RANGE];
    const int b = blockIdx.x;
    const int nb = b << SHIFT;
    const int nr = min(RANGE, N - nb);
    for (int i = threadIdx.x; i < nr; i += 256) cur[i] = rowp[nb + i];
    __syncthreads();
    const int lo = bin_off[b];
    const int hi = (b + 1 < NB) ? bin_off[b + 1] : E;
    for (int i = lo + threadIdx.x; i < hi; i += 256) {
        unsigned w = pairs[i];
        int pos = atomicAdd(&cur[w >> 23], 1);
        colv1[pos] = w & 0x7fffffu;     // src index only
    }
}

// Merged prep: zero bin_counts + both weight transposes + zero pad row N of
// the xw table (tail slots in agg gather row N with pure adds).
__global__ void prep_kernel(const float* __restrict__ W1, const float* __restrict__ W2,
                            unsigned short* __restrict__ wt1, unsigned short* __restrict__ wt2,
                            int K1, int* __restrict__ bin_counts,
                            unsigned short* __restrict__ xw_pad, int N) {
    int idx = blockIdx.x * 256 + threadIdx.x;
    if (idx < MAXB) bin_counts[idx] = 0;
    if (idx < HID) xw_pad[(size_t)N * HID + idx] = 0;   // zero row N
    if (idx < 128 * K1) {
        int nn = idx / K1, k = idx - nn * K1;
        wt1[(size_t)nn * K1 + k] = f2bf(W1[(size_t)k * 128 + nn]);
    }
    if (idx < 128 * 128) {
        int nn = idx >> 7, k = idx & 127;
        wt2[(size_t)nn * 128 + k] = f2bf(W2[(size_t)k * 128 + nn]);
    }
}

// ------------------------------- GEMM --------------------------------------
// Out[row][col] (bf16, N x 128) = (A (N x K) @ W) * dinv[row]  (pre-scale for
// the agg gather). R12 structure: 16-row waves, K-split 32KB LDS B staging,
// DEPTH=4 A register pipe on vmcnt, 8x ds_read_b128 B per iteration.
template <bool A_BF16, int K>
__global__ __launch_bounds__(256)
void gemm_kernel(const void* __restrict__ Aptr, const unsigned short* __restrict__ Wt,
                 const float* __restrict__ dinvv, unsigned short* __restrict__ Out,
                 int nrows) {
    constexpr int NIT  = K / 32;
    constexpr int DEPTH = (NIT < 4) ? NIT : 4;
    constexpr int HK   = (K > 128) ? (K / 2) : K;   // K staged per phase
    constexpr int CHH  = HK / 8;                    // 16B chunks per col/phase
    constexpr int PH   = K / HK;
    constexpr int NITP = HK / 32;
    __shared__ uint4 sB[128 * CHH];                 // 32 KB

    const int tid  = threadIdx.x;
    const int wave = tid >> 6;
    const int lane = tid & 63;
    const int q = lane >> 4;
    const int r = lane & 15;

    const int wrow = blockIdx.x * 64 + wave * 16;
    const size_t row0 = (size_t)min(wrow + r, nrows - 1);

    const unsigned short* A16 = (const unsigned short*)Aptr;
    const float*          A32 = (const float*)Aptr;

    f32x4 acc[8];
#pragma unroll
    for (int c = 0; c < 8; ++c) acc[c] = (f32x4){0.f, 0.f, 0.f, 0.f};

    bf16x8 preb[DEPTH];
    float4 pref[DEPTH][2];

    // prologue: fill the A pipe
#pragma unroll
    for (int i = 0; i < DEPTH; ++i) {
        const int kk = i * 32 + q * 8;
        if (A_BF16) {
            preb[i] = *reinterpret_cast<const bf16x8*>(A16 + row0 * K + kk);
        } else {
            pref[i][0] = *reinterpret_cast<const float4*>(A32 + row0 * K + kk);
            pref[i][1] = *reinterpret_cast<const float4*>(A32 + row0 * K + kk + 4);
        }
    }

#pragma unroll
    for (int ph = 0; ph < PH; ++ph) {
        if (ph) __syncthreads();
        // stage this phase's B half (coalesced; swizzled chunk placement)
        for (int idx = tid; idx < 128 * CHH; idx += 256) {
            const int col = idx / CHH;
            const int kc  = idx & (CHH - 1);
            const uint4 v = *reinterpret_cast<const uint4*>(
                Wt + (size_t)col * K + ph * HK + kc * 8);
            sB[col * CHH + (kc ^ (col & (CHH - 1)))] = v;
        }
        __syncthreads();

#pragma unroll
        for (int itp = 0; itp < NITP; ++itp) {
            const int git  = ph * NITP + itp;
            const int slot = git % DEPTH;

            // B fragments for this K-step from swizzled LDS
            bf16x8 bcur[8];
#pragma unroll
            for (int c = 0; c < 8; ++c) {
                const int col = c * 16 + r;
                const int chunk = (itp * 4 + q) ^ (col & (CHH - 1));
                bcur[c] = *reinterpret_cast<const bf16x8*>(&sB[col * CHH + chunk]);
            }

            // consume oldest A slot (vmcnt waits only on A pipe); cvt VALU
            // work overlaps the ds_read latency of bcur
            bf16x8 afrag;
            if (A_BF16) {
                afrag = preb[slot];
            } else {
                const float4 x0 = pref[slot][0];
                const float4 x1 = pref[slot][1];
                bf16x8 a;
                a[0] = (__bf16)x0.x; a[1] = (__bf16)x0.y; a[2] = (__bf16)x0.z; a[3] = (__bf16)x0.w;
                a[4] = (__bf16)x1.x; a[5] = (__bf16)x1.y; a[6] = (__bf16)x1.z; a[7] = (__bf16)x1.w;
                afrag = a;
            }

            // refill the pipe slot (stays in flight across iterations)
            if (git + DEPTH < NIT) {
                const int kk2 = (git + DEPTH) * 32 + q * 8;
                if (A_BF16) {
                    preb[slot] = *reinterpret_cast<const bf16x8*>(A16 + row0 * K + kk2);
                } else {
                    pref[slot][0] = *reinterpret_cast<const float4*>(A32 + row0 * K + kk2);
                    pref[slot][1] = *reinterpret_cast<const float4*>(A32 + row0 * K + kk2 + 4);
                }
            }

#pragma unroll
            for (int c = 0; c < 8; ++c)
                acc[c] = __builtin_amdgcn_mfma_f32_16x16x32_bf16(afrag, bcur[c], acc[c], 0, 0, 0);
        }
    }

#pragma unroll
    for (int v = 0; v < 4; ++v) {
        const int row = wrow + q * 4 + v;
        if (row < nrows) {
            const float sc = dinvv[row];
#pragma unroll
            for (int c = 0; c < 8; ++c)
                Out[(size_t)row * 128 + c * 16 + r] = f2bf(acc[c][v] * sc);
        }
    }
}

// --------------------------- Aggregation -----------------------------------
// R16: R10/R12 launch shape (one node per 16-lane quarter, one-shot blocks)
// + R15 math (pure v_pk_add consume on dinv-pre-scaled rows, bare-src colv,
// zero-row-N tails, per-quarter self-loop). Depth-16 issue pipe per
// 16-edge chunk; next chunk's colv word prefetched.

#define AGG_ISSUE(g, TBL)                                                     \
    if ((g) * 4 < cnt) {                                                      \
        _Pragma("unroll")                                                     \
        for (int j = 0; j < 4; ++j) {                                         \
            const int sl = (g) * 4 + j;                                       \
            const unsigned cg = (unsigned)__shfl((int)cw, qb + sl);           \
            pf[sl] = *reinterpret_cast<const uint4*>(                         \
                (const char*)(TBL) + (((size_t)cg << 8) + coff));             \
        }                                                                     \
    }

#define AGG_CONS(g)                                                          \
    if ((g) * 4 < cnt) {                                                     \
        _Pragma("unroll")                                                    \
        for (int j = 0; j < 4; ++j) {                                        \
            const uint4 uu = pf[(g) * 4 + j];                                \
            A0 += (f32x2){bflo(uu.x), bfhi(uu.x)};                           \
            A1 += (f32x2){bflo(uu.y), bfhi(uu.y)};                           \
            A2 += (f32x2){bflo(uu.z), bfhi(uu.z)};                           \
            A3 += (f32x2){bflo(uu.w), bfhi(uu.w)};                           \
        }                                                                    \
    }

#define AGG_EDGE_LOOP(TBL)                                                   \
    unsigned cw = (beg + c < end) ? colv1[beg + c] : (unsigned)n;            \
    for (int eb = beg; eb < end; eb += 16) {                                 \
        const int cnt = end - eb;                                            \
        AGG_ISSUE(0, TBL) AGG_ISSUE(1, TBL) AGG_ISSUE(2, TBL) AGG_ISSUE(3, TBL) \
        unsigned cw_next = (unsigned)n;                                      \
        if (eb + 16 + c < end) cw_next = colv1[eb + 16 + c];                 \
        AGG_CONS(0) AGG_CONS(1) AGG_CONS(2) AGG_CONS(3)                      \
        cw = cw_next;                                                        \
    }

__device__ __forceinline__ f32x2 __shfl_xor(f32x2 v, int m) {
    return (f32x2){__shfl_xor(v[0], m), __shfl_xor(v[1], m)};
}

__global__ __launch_bounds__(256)
void agg1_kernel(const unsigned short* __restrict__ xw, const unsigned* __restrict__ colv1,
                 const int* __restrict__ rowp, const float* __restrict__ dinv,
                 const float* __restrict__ b1, const float* __restrict__ Wc,
                 const float* __restrict__ bc, uint4* __restrict__ h1,
                 float* __restrict__ outp, int n) {
    const int node = blockIdx.x * 16 + (threadIdx.x >> 4);
    if (node >= n) return;
    const int lane = threadIdx.x & 63;
    const int c    = lane & 15;
    const int qb   = lane & 48;               // quarter base lane
    const unsigned coff = (unsigned)c << 4;
    const float di = dinv[node];
    const int beg = rowp[node], end = rowp[node + 1];

    // self-loop row (pre-scaled by dinv[node]); every quarter adds its own
    const uint4 su = *reinterpret_cast<const uint4*>(
        (const char*)xw + (((size_t)node << 8) + coff));

    f32x2 A0 = {0.f,0.f}, A1 = {0.f,0.f}, A2 = {0.f,0.f}, A3 = {0.f,0.f};
    uint4 pf[16];

    AGG_EDGE_LOOP(xw)

    A0 += (f32x2){bflo(su.x), bfhi(su.x)};
    A1 += (f32x2){bflo(su.y), bfhi(su.y)};
    A2 += (f32x2){bflo(su.z), bfhi(su.z)};
    A3 += (f32x2){bflo(su.w), bfhi(su.w)};

    const float4 bb0 = reinterpret_cast<const float4*>(b1)[2*c];
    const float4 bb1 = reinterpret_cast<const float4*>(b1)[2*c + 1];
    float a0 = fmaxf(A0[0]*di + bb0.x, 0.f), a1 = fmaxf(A0[1]*di + bb0.y, 0.f);
    float a2 = fmaxf(A1[0]*di + bb0.z, 0.f), a3 = fmaxf(A1[1]*di + bb0.w, 0.f);
    float a4 = fmaxf(A2[0]*di + bb1.x, 0.f), a5 = fmaxf(A2[1]*di + bb1.y, 0.f);
    float a6 = fmaxf(A3[0]*di + bb1.z, 0.f), a7 = fmaxf(A3[1]*di + bb1.w, 0.f);

    h1[((size_t)node << 4) + c] =
        make_uint4(packbf(a0,a1), packbf(a2,a3), packbf(a4,a5), packbf(a6,a7));

    const float4 w0 = reinterpret_cast<const float4*>(Wc)[4*c];
    const float4 w1 = reinterpret_cast<const float4*>(Wc)[4*c + 1];
    const float4 w2 = reinterpret_cast<const float4*>(Wc)[4*c + 2];
    const float4 w3 = reinterpret_cast<const float4*>(Wc)[4*c + 3];
    float c0 = a0*w0.x + a1*w0.z + a2*w1.x + a3*w1.z
             + a4*w2.x + a5*w2.z + a6*w3.x + a7*w3.z;
    float c1 = a0*w0.y + a1*w0.w + a2*w1.y + a3*w1.w
             + a4*w2.y + a5*w2.w + a6*w3.y + a7*w3.w;
#pragma unroll
    for (int off = 1; off < 16; off <<= 1) {       // quarter-local reduce
        c0 += __shfl_xor(c0, off);
        c1 += __shfl_xor(c1, off);
    }
    if (c == 0) {
        outp[2 * (size_t)node]     = 0.5f * (c0 + bc[0]);
        outp[2 * (size_t)node + 1] = 0.5f * (c1 + bc[1]);
    }
}

__global__ __launch_bounds__(256)
void agg2_kernel(const unsigned short* __restrict__ xw2, const uint4* __restrict__ h1,
                 const unsigned* __restrict__ colv1, const int* __restrict__ rowp,
                 const float* __restrict__ dinv, const float* __restrict__ b2,
                 const float* __restrict__ Wf, const float* __restrict__ bfv,
                 const float* __restrict__ hnode, float* __restrict__ outp, int n) {
    const int node = blockIdx.x * 16 + (threadIdx.x >> 4);
    if (node >= n) return;
    const int lane = threadIdx.x & 63;
    const int c    = lane & 15;
    const int qb   = lane & 48;
    const unsigned coff = (unsigned)c << 4;
    const float di = dinv[node];
    const int beg = rowp[node], end = rowp[node + 1];

    const uint4 su = *reinterpret_cast<const uint4*>(
        (const char*)xw2 + (((size_t)node << 8) + coff));

    f32x2 A0 = {0.f,0.f}, A1 = {0.f,0.f}, A2 = {0.f,0.f}, A3 = {0.f,0.f};
    uint4 pf[16];

    AGG_EDGE_LOOP(xw2)

    A0 += (f32x2){bflo(su.x), bfhi(su.x)};
    A1 += (f32x2){bflo(su.y), bfhi(su.y)};
    A2 += (f32x2){bflo(su.z), bfhi(su.z)};
    A3 += (f32x2){bflo(su.w), bfhi(su.w)};

    const float4 bb0 = reinterpret_cast<const float4*>(b2)[2*c];
    const float4 bb1 = reinterpret_cast<const float4*>(b2)[2*c + 1];
    float h20 = fmaxf(A0[0]*di + bb0.x, 0.f), h21 = fmaxf(A0[1]*di + bb0.y, 0.f);
    float h22 = fmaxf(A1[0]*di + bb0.z, 0.f), h23 = fmaxf(A1[1]*di + bb0.w, 0.f);
    float h24 = fmaxf(A2[0]*di + bb1.x, 0.f), h25 = fmaxf(A2[1]*di + bb1.y, 0.f);
    float h26 = fmaxf(A3[0]*di + bb1.z, 0.f), h27 = fmaxf(A3[1]*di + bb1.w, 0.f);

    const float alpha = hnode[node];
    const float beta  = 1.f - alpha;
    const uint4 hh = h1[((size_t)node << 4) + c];
    const float ha0 = alpha*h20 + beta*bflo(hh.x);
    const float ha1 = alpha*h21 + beta*bfhi(hh.x);
    const float ha2 = alpha*h22 + beta*bflo(hh.y);
    const float ha3 = alpha*h23 + beta*bfhi(hh.y);
    const float ha4 = alpha*h24 + beta*bflo(hh.z);
    const float ha5 = alpha*h25 + beta*bfhi(hh.z);
    const float ha6 = alpha*h26 + beta*bflo(hh.w);
    const float ha7 = alpha*h27 + beta*bfhi(hh.w);

    const float4 w0 = reinterpret_cast<const float4*>(Wf)[4*c];
    const float4 w1 = reinterpret_cast<const float4*>(Wf)[4*c + 1];
    const float4 w2 = reinterpret_cast<const float4*>(Wf)[4*c + 2];
    const float4 w3 = reinterpret_cast<const float4*>(Wf)[4*c + 3];
    float f0 = ha0*w0.x + ha1*w0.z + ha2*w1.x + ha3*w1.z
             + ha4*w2.x + ha5*w2.z + ha6*w3.x + ha7*w3.z;
    float f1 = ha0*w0.y + ha1*w0.w + ha2*w1.y + ha3*w1.w
             + ha4*w2.y + ha5*w2.w + ha6*w3.y + ha7*w3.w;
#pragma unroll
    for (int off = 1; off < 16; off <<= 1) {
        f0 += __shfl_xor(f0, off);
        f1 += __shfl_xor(f1, off);
    }
    if (c == 0) {
        outp[2 * (size_t)node]     += 0.5f * (f0 + bfv[0]);
        outp[2 * (size_t)node + 1] += 0.5f * (f1 + bfv[1]);
    }
}

// ------------------------------ launch -------------------------------------

extern "C" void kernel_launch(void* const* d_in, const int* in_sizes, int n_in,
                              void* d_out, int out_size, void* d_ws, size_t ws_size,
                              hipStream_t stream) {
    const float* x     = (const float*)d_in[0];
    const int*   ei    = (const int*)d_in[1];     // int32 per harness contract
    const float* hnode = (const float*)d_in[2];
    const float* W1    = (const float*)d_in[3];
    const float* b1    = (const float*)d_in[4];
    const float* W2    = (const float*)d_in[5];
    const float* b2    = (const float*)d_in[6];
    const float* Wc    = (const float*)d_in[7];
    const float* bc    = (const float*)d_in[8];
    const float* Wf    = (const float*)d_in[9];
    const float* bfv   = (const float*)d_in[10];

    const int N  = in_sizes[2];
    const int E  = in_sizes[1] / 2;
    const int K1 = in_sizes[3] / HID;   // 256 (fixed by problem shape)
    const int NB = (N + RANGE - 1) >> SHIFT;
    const int* srcv = ei;
    const int* dstv = ei + E;
    float* outp = (float*)d_out;

    char* ws = (char*)d_ws;
    size_t off = 0;
    auto alloc = [&](size_t bytes) -> char* {
        char* p = ws + off;
        off += (bytes + 255) & ~(size_t)255;
        return p;
    };
    unsigned short* xw       = (unsigned short*)alloc((size_t)(N + 1) * HID * 2); // +pad row N
    unsigned short* h1       = (unsigned short*)alloc((size_t)N * HID * 2);
    float*          dinv     = (float*)alloc((size_t)N * 4);
    int*            rowp     = (int*)alloc((size_t)(N + 1) * 4);
    unsigned*       colv1    = (unsigned*)alloc((size_t)E * 4);
    unsigned*       pairs    = (unsigned*)alloc((size_t)E * 4);
    int*            bin_counts = (int*)alloc(MAXB * 4);
    int*            bin_off    = (int*)alloc(MAXB * 4);
    int*            bin_cur    = (int*)alloc(MAXB * 4);
    unsigned short* wt1      = (unsigned short*)alloc((size_t)HID * K1 * 2);
    unsigned short* wt2      = (unsigned short*)alloc((size_t)HID * HID * 2);

    prep_kernel<<<(HID * K1 + 255) / 256, 256, 0, stream>>>(W1, W2, wt1, wt2, K1,
                                                            bin_counts, xw, N);

    const int ntiles = (E + TILE - 1) / TILE;
    bincount_kernel<<<ntiles, 256, 0, stream>>>(dstv, bin_counts, E, NB);
    binscan_kernel<<<1, 256, 0, stream>>>(bin_counts, bin_off, bin_cur, NB);
    stage_kernel<<<ntiles, 256, 0, stream>>>(srcv, dstv, bin_cur, pairs, E);
    binrowp_kernel<<<NB, 256, 0, stream>>>(pairs, bin_off, dinv, rowp, N, NB, E);
    fine_kernel<<<NB, 256, 0, stream>>>(pairs, bin_off, rowp, dinv, colv1, N, NB, E);

    gemm_kernel<false, 256><<<(N + 63) / 64, 256, 0, stream>>>((const void*)x, wt1, dinv, xw, N);
    agg1_kernel<<<(N + 15) / 16, 256, 0, stream>>>(xw, colv1, rowp, dinv,
                                                   b1, Wc, bc, (uint4*)h1, outp, N);
    gemm_kernel<true, 128><<<(N + 63) / 64, 256, 0, stream>>>((const void*)h1, wt2, dinv, xw, N);
    agg2_kernel<<<(N + 15) / 16, 256, 0, stream>>>(xw, (const uint4*)h1, colv1,
                                                   rowp, dinv, b2, Wf, bfv, hnode, outp, N);
}

// Round 11
// 373.593 us; speedup vs baseline: 1.0521x; 1.0004x over previous
//
#include <hip/hip_runtime.h>

// ---------------------------------------------------------------------------
// GCN 2-layer fused pipeline for MI355X (gfx950)
//   h1 = relu(Dinv (A+I) Dinv (x@W1) + b1)
//   out = 0.5*(h1@Wc + bc) + 0.5*((alpha*h2 + (1-alpha)*h1)@Wf + bf)
//   h2 = relu(Dinv (A+I) Dinv (h1@W2) + b2)
// R2: binned counting-sort CSR. R10: agg one-node-per-QUARTER depth-16 pipe.
// R12: occupancy-first GEMM (16-row waves, K-split 32KB LDS B).
// R14/R15/R16: dinv[src] pre-scaled in gemm epilogue -> agg consume is pure
// v_pk_add; bare-src colv; zero-row-N tails; one-shot agg launch.
// AGG FLOOR ESTABLISHED: 59.7/59.9us at ~3.4-3.6 TB/s gather delivery across
// FOUR structurally distinct agg implementations (R10/R13/R15/R16) -> the
// random-256B-row L2-miss/fabric path is saturated; agg is done.
// R17: gemm-only edits (agg untouched): (a) B staged via global_load_lds
// width=16 with PRE-SWIZZLED global source (m97/m173 pattern; XOR swizzle is
// an involution so the LDS image is identical; dest linear in tid =
// wave-uniform base + lane*16); (b) fp32 A-pipe DEPTH 4->5 (one more K-step
// of latency margin, est ~125 VGPR keeps 4 waves/SIMD).
// (R17 resubmit: previous round failed on GPU acquisition, never measured.)
// ---------------------------------------------------------------------------

#define HID 128
#define SHIFT 9
#define RANGE 512           // nodes per bin = 1<<SHIFT
#define MAXB 256            // max bins (N <= 131072)
#define TILE 4096           // edges per stage block

typedef __bf16 bf16x8 __attribute__((ext_vector_type(8)));
typedef float  f32x4  __attribute__((ext_vector_type(4)));
typedef float  f32x2  __attribute__((ext_vector_type(2)));

__device__ __forceinline__ unsigned short f2bf(float x) {
    unsigned int b = __float_as_uint(x);
    b += 0x7fffu + ((b >> 16) & 1u);     // round-to-nearest-even
    return (unsigned short)(b >> 16);
}
__device__ __forceinline__ float bflo(unsigned int u) { return __uint_as_float(u << 16); }
__device__ __forceinline__ float bfhi(unsigned int u) { return __uint_as_float(u & 0xffff0000u); }
__device__ __forceinline__ unsigned packbf(float a, float b) {
    return (unsigned)f2bf(a) | ((unsigned)f2bf(b) << 16);
}

// --------------------------- binned CSR build ------------------------------

__global__ __launch_bounds__(256)
void bincount_kernel(const int* __restrict__ dst, int* __restrict__ bin_counts,
                     int E, int NB) {
    __shared__ int h[MAXB];
    for (int i = threadIdx.x; i < NB; i += 256) h[i] = 0;
    __syncthreads();
    const int base = blockIdx.x * TILE;
#pragma unroll
    for (int j = 0; j < TILE; j += 256) {
        int e = base + j + threadIdx.x;
        if (e < E) atomicAdd(&h[((unsigned)dst[e]) >> SHIFT], 1);
    }
    __syncthreads();
    for (int i = threadIdx.x; i < NB; i += 256) {
        int v = h[i];
        if (v) atomicAdd(&bin_counts[i], v);
    }
}

__global__ void binscan_kernel(const int* __restrict__ bin_counts,
                               int* __restrict__ bin_off, int* __restrict__ bin_cur, int NB) {
    __shared__ int sh[MAXB];
    const int t = threadIdx.x;
    int v = (t < NB) ? bin_counts[t] : 0;
    sh[t] = v;
    __syncthreads();
    for (int s = 1; s < 256; s <<= 1) {
        int x = (t >= s) ? sh[t - s] : 0;
        __syncthreads();
        sh[t] += x;
        __syncthreads();
    }
    if (t < NB) {
        int ex = sh[t] - v;     // exclusive
        bin_off[t] = ex;
        bin_cur[t] = ex;
    }
}

// Block-level binning: tile-local LDS sort by bin, then bin-sorted write-out
// in contiguous runs. pairs[i] = (dlocal<<23) | src   (src < 2^23).
__global__ __launch_bounds__(256)
void stage_kernel(const int* __restrict__ src, const int* __restrict__ dst,
                  int* __restrict__ bin_cur, unsigned* __restrict__ pairs, int E) {
    __shared__ int sh_hist[MAXB];
    __shared__ int sh_off[MAXB];
    __shared__ int sh_ex[MAXB];
    __shared__ int sh_gbase[MAXB];
    __shared__ uint2 stg[TILE];
    const int t = threadIdx.x;
    const int base = blockIdx.x * TILE;
    const int cnt = min(TILE, E - base);

    for (int i = t; i < MAXB; i += 256) sh_hist[i] = 0;
    __syncthreads();

    int s[16], d[16], r[16];
#pragma unroll
    for (int j = 0; j < 16; ++j) {
        const int k = j * 256 + t;
        if (k < cnt) {
            s[j] = src[base + k];
            d[j] = dst[base + k];
            r[j] = atomicAdd(&sh_hist[((unsigned)d[j]) >> SHIFT], 1);
        }
    }
    __syncthreads();

    const int hv = sh_hist[t];
    sh_off[t] = hv;
    __syncthreads();
    for (int st = 1; st < 256; st <<= 1) {
        int x = (t >= st) ? sh_off[t - st] : 0;
        __syncthreads();
        sh_off[t] += x;
        __syncthreads();
    }
    sh_ex[t] = sh_off[t] - hv;                      // exclusive within tile
    if (hv > 0) sh_gbase[t] = atomicAdd(&bin_cur[t], hv);
    __syncthreads();

#pragma unroll
    for (int j = 0; j < 16; ++j) {
        const int k = j * 256 + t;
        if (k < cnt) {
            int b = ((unsigned)d[j]) >> SHIFT;
            stg[sh_ex[b] + r[j]] = make_uint2((unsigned)s[j], (unsigned)d[j]);
        }
    }
    __syncthreads();

    for (int i = t; i < cnt; i += 256) {
        uint2 p = stg[i];
        int b = (int)(p.y >> SHIFT);
        unsigned w = ((p.y & (RANGE - 1)) << 23) | p.x;
        pairs[sh_gbase[b] + (i - sh_ex[b])] = w;
    }
}

// Per-bin: histogram pairs -> counts; intra-bin scan (+bin_off base) -> rowp;
// dinv from counts.
__global__ __launch_bounds__(256)
void binrowp_kernel(const unsigned* __restrict__ pairs, const int* __restrict__ bin_off,
                    float* __restrict__ dinv, int* __restrict__ rowp,
                    int N, int NB, int E) {
    __shared__ int c[RANGE];
    __shared__ int sh[256];
    const int b = blockIdx.x;
    const int t = threadIdx.x;
    const int nb = b << SHIFT;
    const int nr = min(RANGE, N - nb);
    for (int i = t; i < RANGE; i += 256) c[i] = 0;
    __syncthreads();
    const int lo = bin_off[b];
    const int hi = (b + 1 < NB) ? bin_off[b + 1] : E;
    for (int i = lo + t; i < hi; i += 256)
        atomicAdd(&c[pairs[i] >> 23], 1);
    __syncthreads();
    const int v0 = c[2 * t], v1 = c[2 * t + 1];
    const int pr = v0 + v1;
    sh[t] = pr;
    __syncthreads();
    for (int s = 1; s < 256; s <<= 1) {
        int x = (t >= s) ? sh[t - s] : 0;
        __syncthreads();
        sh[t] += x;
        __syncthreads();
    }
    const int ex = sh[t] - pr + lo;     // exclusive prefix + bin edge base
    if (2 * t < nr) {
        rowp[nb + 2 * t] = ex;
        dinv[nb + 2 * t] = rsqrtf((float)(v0 + 1));
    }
    if (2 * t + 1 < nr) {
        rowp[nb + 2 * t + 1] = ex + v0;
        dinv[nb + 2 * t + 1] = rsqrtf((float)(v1 + 1));
    }
    if (b == 0 && t == 0) rowp[N] = E;
}

// Per-bin fine scatter; emits bare src index (dinv[src] is pre-scaled into
// the gathered rows by the GEMM epilogue)
__global__ __launch_bounds__(256)
void fine_kernel(const unsigned* __restrict__ pairs, const int* __restrict__ bin_off,
                 const int* __restrict__ rowp, const float* __restrict__ dinv,
                 unsigned* __restrict__ colv1, int N, int NB, int E) {
    __shared__ int cur[RANGE];
    const int b = blockIdx.x;
    const int nb = b << SHIFT;
    const int nr = min(RANGE, N - nb);
    for (int i = threadIdx.x; i < nr; i += 256) cur[i] = rowp[nb + i];
    __syncthreads();
    const int lo = bin_off[b];
    const int hi = (b + 1 < NB) ? bin_off[b + 1] : E;
    for (int i = lo + threadIdx.x; i < hi; i += 256) {
        unsigned w = pairs[i];
        int pos = atomicAdd(&cur[w >> 23], 1);
        colv1[pos] = w & 0x7fffffu;     // src index only
    }
}

// Merged prep: zero bin_counts + both weight transposes + zero pad row N of
// the xw table (tail slots in agg gather row N with pure adds).
__global__ void prep_kernel(const float* __restrict__ W1, const float* __restrict__ W2,
                            unsigned short* __restrict__ wt1, unsigned short* __restrict__ wt2,
                            int K1, int* __restrict__ bin_counts,
                            unsigned short* __restrict__ xw_pad, int N) {
    int idx = blockIdx.x * 256 + threadIdx.x;
    if (idx < MAXB) bin_counts[idx] = 0;
    if (idx < HID) xw_pad[(size_t)N * HID + idx] = 0;   // zero row N
    if (idx < 128 * K1) {
        int nn = idx / K1, k = idx - nn * K1;
        wt1[(size_t)nn * K1 + k] = f2bf(W1[(size_t)k * 128 + nn]);
    }
    if (idx < 128 * 128) {
        int nn = idx >> 7, k = idx & 127;
        wt2[(size_t)nn * 128 + k] = f2bf(W2[(size_t)k * 128 + nn]);
    }
}

// ------------------------------- GEMM --------------------------------------
// Out[row][col] (bf16, N x 128) = (A (N x K) @ W) * dinv[row]  (pre-scale for
// the agg gather). R12 structure: 16-row waves, K-split 32KB LDS B staging,
// A register pipe on vmcnt, 8x ds_read_b128 B per iteration.
// R17: B staged via global_load_lds width=16; swizzle applied to the GLOBAL
// source address (involution -> identical LDS image), dest linear in tid.
template <bool A_BF16, int K>
__global__ __launch_bounds__(256)
void gemm_kernel(const void* __restrict__ Aptr, const unsigned short* __restrict__ Wt,
                 const float* __restrict__ dinvv, unsigned short* __restrict__ Out,
                 int nrows) {
    constexpr int NIT  = K / 32;
    constexpr int DEPTH = A_BF16 ? ((NIT < 4) ? NIT : 4) : ((NIT < 5) ? NIT : 5);
    constexpr int HK   = (K > 128) ? (K / 2) : K;   // K staged per phase
    constexpr int CHH  = HK / 8;                    // 16B chunks per col/phase
    constexpr int PH   = K / HK;
    constexpr int NITP = HK / 32;
    __shared__ uint4 sB[128 * CHH];                 // 32 KB

    const int tid  = threadIdx.x;
    const int wave = tid >> 6;
    const int lane = tid & 63;
    const int q = lane >> 4;
    const int r = lane & 15;

    const int wrow = blockIdx.x * 64 + wave * 16;
    const size_t row0 = (size_t)min(wrow + r, nrows - 1);

    const unsigned short* A16 = (const unsigned short*)Aptr;
    const float*          A32 = (const float*)Aptr;

    f32x4 acc[8];
#pragma unroll
    for (int c = 0; c < 8; ++c) acc[c] = (f32x4){0.f, 0.f, 0.f, 0.f};

    bf16x8 preb[DEPTH];
    float4 pref[DEPTH][2];

    // prologue: fill the A pipe
#pragma unroll
    for (int i = 0; i < DEPTH; ++i) {
        const int kk = i * 32 + q * 8;
        if (A_BF16) {
            preb[i] = *reinterpret_cast<const bf16x8*>(A16 + row0 * K + kk);
        } else {
            pref[i][0] = *reinterpret_cast<const float4*>(A32 + row0 * K + kk);
            pref[i][1] = *reinterpret_cast<const float4*>(A32 + row0 * K + kk + 4);
        }
    }

#pragma unroll
    for (int ph = 0; ph < PH; ++ph) {
        if (ph) __syncthreads();
        // stage this phase's B half direct-to-LDS: dest linear in tid (wave-
        // uniform base + lane*16), source pre-swizzled (XOR involution)
        for (int idx = tid; idx < 128 * CHH; idx += 256) {
            const int col = idx / CHH;
            const int kc  = idx & (CHH - 1);
            const unsigned short* srcp =
                Wt + (size_t)col * K + ph * HK + (size_t)(kc ^ (col & (CHH - 1))) * 8;
            __builtin_amdgcn_global_load_lds(
                (const __attribute__((address_space(1))) unsigned int*)srcp,
                (__attribute__((address_space(3))) unsigned int*)&sB[idx],
                16, 0, 0);
        }
        __syncthreads();

#pragma unroll
        for (int itp = 0; itp < NITP; ++itp) {
            const int git  = ph * NITP + itp;
            const int slot = git % DEPTH;

            // B fragments for this K-step from swizzled LDS
            bf16x8 bcur[8];
#pragma unroll
            for (int c = 0; c < 8; ++c) {
                const int col = c * 16 + r;
                const int chunk = (itp * 4 + q) ^ (col & (CHH - 1));
                bcur[c] = *reinterpret_cast<const bf16x8*>(&sB[col * CHH + chunk]);
            }

            // consume oldest A slot (vmcnt waits only on A pipe); cvt VALU
            // work overlaps the ds_read latency of bcur
            bf16x8 afrag;
            if (A_BF16) {
                afrag = preb[slot];
            } else {
                const float4 x0 = pref[slot][0];
                const float4 x1 = pref[slot][1];
                bf16x8 a;
                a[0] = (__bf16)x0.x; a[1] = (__bf16)x0.y; a[2] = (__bf16)x0.z; a[3] = (__bf16)x0.w;
                a[4] = (__bf16)x1.x; a[5] = (__bf16)x1.y; a[6] = (__bf16)x1.z; a[7] = (__bf16)x1.w;
                afrag = a;
            }

            // refill the pipe slot (stays in flight across iterations)
            if (git + DEPTH < NIT) {
                const int kk2 = (git + DEPTH) * 32 + q * 8;
                if (A_BF16) {
                    preb[slot] = *reinterpret_cast<const bf16x8*>(A16 + row0 * K + kk2);
                } else {
                    pref[slot][0] = *reinterpret_cast<const float4*>(A32 + row0 * K + kk2);
                    pref[slot][1] = *reinterpret_cast<const float4*>(A32 + row0 * K + kk2 + 4);
                }
            }

#pragma unroll
            for (int c = 0; c < 8; ++c)
                acc[c] = __builtin_amdgcn_mfma_f32_16x16x32_bf16(afrag, bcur[c], acc[c], 0, 0, 0);
        }
    }

#pragma unroll
    for (int v = 0; v < 4; ++v) {
        const int row = wrow + q * 4 + v;
        if (row < nrows) {
            const float sc = dinvv[row];
#pragma unroll
            for (int c = 0; c < 8; ++c)
                Out[(size_t)row * 128 + c * 16 + r] = f2bf(acc[c][v] * sc);
        }
    }
}

// --------------------------- Aggregation -----------------------------------
// R16 (FLOOR-CONFIRMED, do not restructure): one node per 16-lane quarter,
// one-shot blocks. Rows gathered are PRE-SCALED by dinv[src] (gemm
// epilogue) -> consume is pure v_pk_add. Tail slots gather the zeroed row N
// (branchless). Self-loop added per quarter. Depth-16 issue pipe per
// 16-edge chunk; next chunk's colv word prefetched.

#define AGG_ISSUE(g, TBL)                                                     \
    if ((g) * 4 < cnt) {                                                      \
        _Pragma("unroll")                                                     \
        for (int j = 0; j < 4; ++j) {                                         \
            const int sl = (g) * 4 + j;                                       \
            const unsigned cg = (unsigned)__shfl((int)cw, qb + sl);           \
            pf[sl] = *reinterpret_cast<const uint4*>(                         \
                (const char*)(TBL) + (((size_t)cg << 8) + coff));             \
        }                                                                     \
    }

#define AGG_CONS(g)                                                          \
    if ((g) * 4 < cnt) {                                                     \
        _Pragma("unroll")                                                    \
        for (int j = 0; j < 4; ++j) {                                        \
            const uint4 uu = pf[(g) * 4 + j];                                \
            A0 += (f32x2){bflo(uu.x), bfhi(uu.x)};                           \
            A1 += (f32x2){bflo(uu.y), bfhi(uu.y)};                           \
            A2 += (f32x2){bflo(uu.z), bfhi(uu.z)};                           \
            A3 += (f32x2){bflo(uu.w), bfhi(uu.w)};                           \
        }                                                                    \
    }

#define AGG_EDGE_LOOP(TBL)                                                   \
    unsigned cw = (beg + c < end) ? colv1[beg + c] : (unsigned)n;            \
    for (int eb = beg; eb < end; eb += 16) {                                 \
        const int cnt = end - eb;                                            \
        AGG_ISSUE(0, TBL) AGG_ISSUE(1, TBL) AGG_ISSUE(2, TBL) AGG_ISSUE(3, TBL) \
        unsigned cw_next = (unsigned)n;                                      \
        if (eb + 16 + c < end) cw_next = colv1[eb + 16 + c];                 \
        AGG_CONS(0) AGG_CONS(1) AGG_CONS(2) AGG_CONS(3)                      \
        cw = cw_next;                                                        \
    }

__device__ __forceinline__ f32x2 __shfl_xor(f32x2 v, int m) {
    return (f32x2){__shfl_xor(v[0], m), __shfl_xor(v[1], m)};
}

__global__ __launch_bounds__(256)
void agg1_kernel(const unsigned short* __restrict__ xw, const unsigned* __restrict__ colv1,
                 const int* __restrict__ rowp, const float* __restrict__ dinv,
                 const float* __restrict__ b1, const float* __restrict__ Wc,
                 const float* __restrict__ bc, uint4* __restrict__ h1,
                 float* __restrict__ outp, int n) {
    const int node = blockIdx.x * 16 + (threadIdx.x >> 4);
    if (node >= n) return;
    const int lane = threadIdx.x & 63;
    const int c    = lane & 15;
    const int qb   = lane & 48;               // quarter base lane
    const unsigned coff = (unsigned)c << 4;
    const float di = dinv[node];
    const int beg = rowp[node], end = rowp[node + 1];

    // self-loop row (pre-scaled by dinv[node]); every quarter adds its own
    const uint4 su = *reinterpret_cast<const uint4*>(
        (const char*)xw + (((size_t)node << 8) + coff));

    f32x2 A0 = {0.f,0.f}, A1 = {0.f,0.f}, A2 = {0.f,0.f}, A3 = {0.f,0.f};
    uint4 pf[16];

    AGG_EDGE_LOOP(xw)

    A0 += (f32x2){bflo(su.x), bfhi(su.x)};
    A1 += (f32x2){bflo(su.y), bfhi(su.y)};
    A2 += (f32x2){bflo(su.z), bfhi(su.z)};
    A3 += (f32x2){bflo(su.w), bfhi(su.w)};

    const float4 bb0 = reinterpret_cast<const float4*>(b1)[2*c];
    const float4 bb1 = reinterpret_cast<const float4*>(b1)[2*c + 1];
    float a0 = fmaxf(A0[0]*di + bb0.x, 0.f), a1 = fmaxf(A0[1]*di + bb0.y, 0.f);
    float a2 = fmaxf(A1[0]*di + bb0.z, 0.f), a3 = fmaxf(A1[1]*di + bb0.w, 0.f);
    float a4 = fmaxf(A2[0]*di + bb1.x, 0.f), a5 = fmaxf(A2[1]*di + bb1.y, 0.f);
    float a6 = fmaxf(A3[0]*di + bb1.z, 0.f), a7 = fmaxf(A3[1]*di + bb1.w, 0.f);

    h1[((size_t)node << 4) + c] =
        make_uint4(packbf(a0,a1), packbf(a2,a3), packbf(a4,a5), packbf(a6,a7));

    const float4 w0 = reinterpret_cast<const float4*>(Wc)[4*c];
    const float4 w1 = reinterpret_cast<const float4*>(Wc)[4*c + 1];
    const float4 w2 = reinterpret_cast<const float4*>(Wc)[4*c + 2];
    const float4 w3 = reinterpret_cast<const float4*>(Wc)[4*c + 3];
    float c0 = a0*w0.x + a1*w0.z + a2*w1.x + a3*w1.z
             + a4*w2.x + a5*w2.z + a6*w3.x + a7*w3.z;
    float c1 = a0*w0.y + a1*w0.w + a2*w1.y + a3*w1.w
             + a4*w2.y + a5*w2.w + a6*w3.y + a7*w3.w;
#pragma unroll
    for (int off = 1; off < 16; off <<= 1) {       // quarter-local reduce
        c0 += __shfl_xor(c0, off);
        c1 += __shfl_xor(c1, off);
    }
    if (c == 0) {
        outp[2 * (size_t)node]     = 0.5f * (c0 + bc[0]);
        outp[2 * (size_t)node + 1] = 0.5f * (c1 + bc[1]);
    }
}

__global__ __launch_bounds__(256)
void agg2_kernel(const unsigned short* __restrict__ xw2, const uint4* __restrict__ h1,
                 const unsigned* __restrict__ colv1, const int* __restrict__ rowp,
                 const float* __restrict__ dinv, const float* __restrict__ b2,
                 const float* __restrict__ Wf, const float* __restrict__ bfv,
                 const float* __restrict__ hnode, float* __restrict__ outp, int n) {
    const int node = blockIdx.x * 16 + (threadIdx.x >> 4);
    if (node >= n) return;
    const int lane = threadIdx.x & 63;
    const int c    = lane & 15;
    const int qb   = lane & 48;
    const unsigned coff = (unsigned)c << 4;
    const float di = dinv[node];
    const int beg = rowp[node], end = rowp[node + 1];

    const uint4 su = *reinterpret_cast<const uint4*>(
        (const char*)xw2 + (((size_t)node << 8) + coff));

    f32x2 A0 = {0.f,0.f}, A1 = {0.f,0.f}, A2 = {0.f,0.f}, A3 = {0.f,0.f};
    uint4 pf[16];

    AGG_EDGE_LOOP(xw2)

    A0 += (f32x2){bflo(su.x), bfhi(su.x)};
    A1 += (f32x2){bflo(su.y), bfhi(su.y)};
    A2 += (f32x2){bflo(su.z), bfhi(su.z)};
    A3 += (f32x2){bflo(su.w), bfhi(su.w)};

    const float4 bb0 = reinterpret_cast<const float4*>(b2)[2*c];
    const float4 bb1 = reinterpret_cast<const float4*>(b2)[2*c + 1];
    float h20 = fmaxf(A0[0]*di + bb0.x, 0.f), h21 = fmaxf(A0[1]*di + bb0.y, 0.f);
    float h22 = fmaxf(A1[0]*di + bb0.z, 0.f), h23 = fmaxf(A1[1]*di + bb0.w, 0.f);
    float h24 = fmaxf(A2[0]*di + bb1.x, 0.f), h25 = fmaxf(A2[1]*di + bb1.y, 0.f);
    float h26 = fmaxf(A3[0]*di + bb1.z, 0.f), h27 = fmaxf(A3[1]*di + bb1.w, 0.f);

    const float alpha = hnode[node];
    const float beta  = 1.f - alpha;
    const uint4 hh = h1[((size_t)node << 4) + c];
    const float ha0 = alpha*h20 + beta*bflo(hh.x);
    const float ha1 = alpha*h21 + beta*bfhi(hh.x);
    const float ha2 = alpha*h22 + beta*bflo(hh.y);
    const float ha3 = alpha*h23 + beta*bfhi(hh.y);
    const float ha4 = alpha*h24 + beta*bflo(hh.z);
    const float ha5 = alpha*h25 + beta*bfhi(hh.z);
    const float ha6 = alpha*h26 + beta*bflo(hh.w);
    const float ha7 = alpha*h27 + beta*bfhi(hh.w);

    const float4 w0 = reinterpret_cast<const float4*>(Wf)[4*c];
    const float4 w1 = reinterpret_cast<const float4*>(Wf)[4*c + 1];
    const float4 w2 = reinterpret_cast<const float4*>(Wf)[4*c + 2];
    const float4 w3 = reinterpret_cast<const float4*>(Wf)[4*c + 3];
    float f0 = ha0*w0.x + ha1*w0.z + ha2*w1.x + ha3*w1.z
             + ha4*w2.x + ha5*w2.z + ha6*w3.x + ha7*w3.z;
    float f1 = ha0*w0.y + ha1*w0.w + ha2*w1.y + ha3*w1.w
             + ha4*w2.y + ha5*w2.w + ha6*w3.y + ha7*w3.w;
#pragma unroll
    for (int off = 1; off < 16; off <<= 1) {
        f0 += __shfl_xor(f0, off);
        f1 += __shfl_xor(f1, off);
    }
    if (c == 0) {
        outp[2 * (size_t)node]     += 0.5f * (f0 + bfv[0]);
        outp[2 * (size_t)node + 1] += 0.5f * (f1 + bfv[1]);
    }
}

// ------------------------------ launch -------------------------------------

extern "C" void kernel_launch(void* const* d_in, const int* in_sizes, int n_in,
                              void* d_out, int out_size, void* d_ws, size_t ws_size,
                              hipStream_t stream) {
    const float* x     = (const float*)d_in[0];
    const int*   ei    = (const int*)d_in[1];     // int32 per harness contract
    const float* hnode = (const float*)d_in[2];
    const float* W1    = (const float*)d_in[3];
    const float* b1    = (const float*)d_in[4];
    const float* W2    = (const float*)d_in[5];
    const float* b2    = (const float*)d_in[6];
    const float* Wc    = (const float*)d_in[7];
    const float* bc    = (const float*)d_in[8];
    const float* Wf    = (const float*)d_in[9];
    const float* bfv   = (const float*)d_in[10];

    const int N  = in_sizes[2];
    const int E  = in_sizes[1] / 2;
    const int K1 = in_sizes[3] / HID;   // 256 (fixed by problem shape)
    const int NB = (N + RANGE - 1) >> SHIFT;
    const int* srcv = ei;
    const int* dstv = ei + E;
    float* outp = (float*)d_out;

    char* ws = (char*)d_ws;
    size_t off = 0;
    auto alloc = [&](size_t bytes) -> char* {
        char* p = ws + off;
        off += (bytes + 255) & ~(size_t)255;
        return p;
    };
    unsigned short* xw       = (unsigned short*)alloc((size_t)(N + 1) * HID * 2); // +pad row N
    unsigned short* h1       = (unsigned short*)alloc((size_t)N * HID * 2);
    float*          dinv     = (float*)alloc((size_t)N * 4);
    int*            rowp     = (int*)alloc((size_t)(N + 1) * 4);
    unsigned*       colv1    = (unsigned*)alloc((size_t)E * 4);
    unsigned*       pairs    = (unsigned*)alloc((size_t)E * 4);
    int*            bin_counts = (int*)alloc(MAXB * 4);
    int*            bin_off    = (int*)alloc(MAXB * 4);
    int*            bin_cur    = (int*)alloc(MAXB * 4);
    unsigned short* wt1      = (unsigned short*)alloc((size_t)HID * K1 * 2);
    unsigned short* wt2      = (unsigned short*)alloc((size_t)HID * HID * 2);

    prep_kernel<<<(HID * K1 + 255) / 256, 256, 0, stream>>>(W1, W2, wt1, wt2, K1,
                                                            bin_counts, xw, N);

    const int ntiles = (E + TILE - 1) / TILE;
    bincount_kernel<<<ntiles, 256, 0, stream>>>(dstv, bin_counts, E, NB);
    binscan_kernel<<<1, 256, 0, stream>>>(bin_counts, bin_off, bin_cur, NB);
    stage_kernel<<<ntiles, 256, 0, stream>>>(srcv, dstv, bin_cur, pairs, E);
    binrowp_kernel<<<NB, 256, 0, stream>>>(pairs, bin_off, dinv, rowp, N, NB, E);
    fine_kernel<<<NB, 256, 0, stream>>>(pairs, bin_off, rowp, dinv, colv1, N, NB, E);

    gemm_kernel<false, 256><<<(N + 63) / 64, 256, 0, stream>>>((const void*)x, wt1, dinv, xw, N);
    agg1_kernel<<<(N + 15) / 16, 256, 0, stream>>>(xw, colv1, rowp, dinv,
                                                   b1, Wc, bc, (uint4*)h1, outp, N);
    gemm_kernel<true, 128><<<(N + 63) / 64, 256, 0, stream>>>((const void*)h1, wt2, dinv, xw, N);
    agg2_kernel<<<(N + 15) / 16, 256, 0, stream>>>(xw, (const uint4*)h1, colv1,
                                                   rowp, dinv, b2, Wf, bfv, hnode, outp, N);
}